// Round 2
// baseline (471.272 us; speedup 1.0000x reference)
//
#include <hip/hip_runtime.h>
#include <hip/hip_bf16.h>
#include <cstdint>

#define B_ 16
#define C_ 112
#define HW_ 4096
#define HEADS_ 4
#define HD_ 28
#define NWIN_ 256
#define TOPK_ 128
#define D3_ 336
#define SCALE_ 0.18898223650461363f

// ---------------- kernel 0: transpose Wqkv (336x112) -> WqkvT (112x336) ----------------
__global__ void wt_kernel(const float* __restrict__ W, float* __restrict__ WT) {
    int idx = blockIdx.x * 256 + threadIdx.x;
    if (idx < D3_ * C_) {
        int d = idx / C_, c = idx % C_;
        WT[c * D3_ + d] = W[idx];
    }
}

// ---------------- kernel 1: qkv[b][hw][d] = sum_c x[b][c][hw] * Wqkv[d][c] ----------------
// block: 256 thr = 16 d-lanes x 16 hw-groups; tile 64 hw x 64 d (6 d-passes)
__global__ __launch_bounds__(256) void qkv_kernel(const float* __restrict__ x,
                                                  const float* __restrict__ WT,
                                                  float* __restrict__ qkv) {
    __shared__ float xs[C_][64];      // [c][hw_local]
    __shared__ float ws[C_][68];      // [c][d_local], pad 68 keeps 16B align + no conflicts
    const int b = blockIdx.y;
    const int hw0 = blockIdx.x * 64;
    const int tid = threadIdx.x;
    // stage x tile: 112 rows x 64 (float4, coalesced)
    for (int i = tid; i < C_ * 16; i += 256) {
        int c = i >> 4, j4 = (i & 15) << 2;
        *(float4*)&xs[c][j4] = *(const float4*)(x + (((size_t)b * C_ + c) << 12) + hw0 + j4);
    }
    const int tx = tid & 15;   // d-group (4 d each)
    const int tj = tid >> 4;   // hw-group (4 hw each)
    for (int dp = 0; dp < 6; ++dp) {
        const int d0 = dp << 6;
        __syncthreads();   // xs ready / previous pass compute done
        for (int i = tid; i < C_ * 16; i += 256) {
            int c = i >> 4, dl4 = (i & 15) << 2;
            float4 v = make_float4(0.f, 0.f, 0.f, 0.f);
            if (d0 + dl4 < D3_) v = *(const float4*)(WT + c * D3_ + d0 + dl4);
            *(float4*)&ws[c][dl4] = v;
        }
        __syncthreads();
        float acc[4][4];
        #pragma unroll
        for (int i = 0; i < 4; ++i)
            #pragma unroll
            for (int j = 0; j < 4; ++j) acc[i][j] = 0.f;
        #pragma unroll 4
        for (int c = 0; c < C_; ++c) {
            float4 wv = *(const float4*)&ws[c][tx << 2];
            float4 xv = *(const float4*)&xs[c][tj << 2];
            acc[0][0] += wv.x * xv.x; acc[0][1] += wv.x * xv.y; acc[0][2] += wv.x * xv.z; acc[0][3] += wv.x * xv.w;
            acc[1][0] += wv.y * xv.x; acc[1][1] += wv.y * xv.y; acc[1][2] += wv.y * xv.z; acc[1][3] += wv.y * xv.w;
            acc[2][0] += wv.z * xv.x; acc[2][1] += wv.z * xv.y; acc[2][2] += wv.z * xv.z; acc[2][3] += wv.z * xv.w;
            acc[3][0] += wv.w * xv.x; acc[3][1] += wv.w * xv.y; acc[3][2] += wv.w * xv.z; acc[3][3] += wv.w * xv.w;
        }
        const int dbase = d0 + (tx << 2);
        if (dbase < D3_) {
            #pragma unroll
            for (int j = 0; j < 4; ++j) {
                float4 o4 = make_float4(acc[0][j], acc[1][j], acc[2][j], acc[3][j]);
                *(float4*)(qkv + ((size_t)((b << 12) + hw0 + (tj << 2) + j)) * D3_ + dbase) = o4;
            }
        }
    }
}

// ---------------- kernel 2: windowed top-k attention ----------------
// one block per (b, window); 256 threads; loops over 4 heads
__global__ __launch_bounds__(256) void attn_kernel(const float* __restrict__ qkv,
                                                   const int* __restrict__ topk,
                                                   float* __restrict__ obuf) {
    __shared__ float qs[16][C_];       // scaled q rows (all heads)
    __shared__ float kT[HD_][TOPK_];   // K transposed: [c][k]
    __shared__ float vs[TOPK_][32];    // V natural: [k][d], pad 32 (16B-aligned rows)
    __shared__ float ss[16][132];      // scores / attn
    __shared__ float os[16][C_];       // output rows (all heads)
    __shared__ int idxs[TOPK_];
    const int b = blockIdx.y, w = blockIdx.x;
    const int wy = w >> 4, wx = w & 15;
    const int tid = threadIdx.x;
    if (tid < TOPK_) idxs[tid] = topk[w * TOPK_ + tid];
    // stage q (16 rows x 112), scaled
    for (int i = tid; i < 16 * 28; i += 256) {
        int q = i / 28, c4 = (i % 28) << 2;
        int hw = ((wy * 4 + (q >> 2)) << 6) + (wx << 2) + (q & 3);
        float4 v = *(const float4*)(qkv + ((size_t)((b << 12) + hw)) * D3_ + c4);
        v.x *= SCALE_; v.y *= SCALE_; v.z *= SCALE_; v.w *= SCALE_;
        *(float4*)&qs[q][c4] = v;
    }
    __syncthreads();
    for (int h = 0; h < HEADS_; ++h) {
        // ---- gather K (threads 0..127) and V (threads 128..255), 28 floats per row ----
        {
            const int i = tid & 127, sel = tid >> 7;
            const float* src = qkv + ((size_t)((b << 12) + idxs[i])) * D3_ + C_ + sel * C_ + h * HD_;
            if (sel == 0) {
                #pragma unroll
                for (int c4 = 0; c4 < HD_; c4 += 4) {
                    float4 vv = *(const float4*)(src + c4);
                    kT[c4][i] = vv.x; kT[c4 + 1][i] = vv.y; kT[c4 + 2][i] = vv.z; kT[c4 + 3][i] = vv.w;
                }
            } else {
                #pragma unroll
                for (int c4 = 0; c4 < HD_; c4 += 4) {
                    *(float4*)&vs[i][c4] = *(const float4*)(src + c4);
                }
            }
        }
        __syncthreads();
        // ---- scores: thread = (k, q-half); K column cached in registers ----
        {
            const int k = tid & 127, qh = tid >> 7;
            float kcol[HD_];
            #pragma unroll
            for (int c = 0; c < HD_; ++c) kcol[c] = kT[c][k];
            #pragma unroll
            for (int qi = 0; qi < 8; ++qi) {
                const int q = qh * 8 + qi;
                float s = 0.f;
                #pragma unroll
                for (int c4 = 0; c4 < HD_; c4 += 4) {
                    float4 qv = *(const float4*)&qs[q][h * HD_ + c4];
                    s += qv.x * kcol[c4] + qv.y * kcol[c4 + 1] + qv.z * kcol[c4 + 2] + qv.w * kcol[c4 + 3];
                }
                ss[q][k] = s;
            }
        }
        __syncthreads();
        // ---- softmax: 16 threads per row, shuffle-reduce within 16-lane groups ----
        {
            const int q = tid >> 4, l = tid & 15;
            float vals[8];
            float m = -1e30f;
            #pragma unroll
            for (int j = 0; j < 8; ++j) { vals[j] = ss[q][l + (j << 4)]; m = fmaxf(m, vals[j]); }
            #pragma unroll
            for (int sft = 1; sft < 16; sft <<= 1) m = fmaxf(m, __shfl_xor(m, sft, 64));
            float sum = 0.f;
            #pragma unroll
            for (int j = 0; j < 8; ++j) { vals[j] = __expf(vals[j] - m); sum += vals[j]; }
            #pragma unroll
            for (int sft = 1; sft < 16; sft <<= 1) sum += __shfl_xor(sum, sft, 64);
            const float inv = 1.f / sum;
            #pragma unroll
            for (int j = 0; j < 8; ++j) ss[q][l + (j << 4)] = vals[j] * inv;
        }
        __syncthreads();
        // ---- PV: thread = (q, d-pair); d = 2*dg, 2*dg+1 ----
        {
            const int q = tid & 15, dg = tid >> 4;
            const int d = dg << 1;
            float a0 = 0.f, a1 = 0.f;
            #pragma unroll 4
            for (int k = 0; k < TOPK_; ++k) {
                float a = ss[q][k];
                a0 += a * vs[k][d];
                a1 += a * vs[k][d + 1];
            }
            if (d < HD_) {
                os[q][h * HD_ + d] = a0;
                os[q][h * HD_ + d + 1] = a1;
            }
        }
        __syncthreads();
    }
    // write o rows (coalesced float4)
    for (int i = tid; i < 16 * 28; i += 256) {
        int q = i / 28, c4 = (i % 28) << 2;
        int hw = ((wy * 4 + (q >> 2)) << 6) + (wx << 2) + (q & 3);
        *(float4*)(obuf + ((size_t)((b << 12) + hw)) * C_ + c4) = *(float4*)&os[q][c4];
    }
}

// ---------------- kernel 3: out[b][d][hw] = sum_c o[b][hw][c]*Wproj[d][c] + bproj[d] ----------------
// block: 256 thr = 64 hw-rows x 4 d-quarters; o row held in registers, Wproj broadcast from LDS
__global__ __launch_bounds__(256) void proj_kernel(const float* __restrict__ obuf,
                                                   const float* __restrict__ Wp,
                                                   const float* __restrict__ bp,
                                                   float* __restrict__ out) {
    __shared__ float wsh[C_ * C_];
    const int b = blockIdx.y;
    const int hw0 = blockIdx.x * 64;
    const int tid = threadIdx.x;
    for (int i = tid; i < C_ * C_ / 4; i += 256) {
        *(float4*)&wsh[i << 2] = *(const float4*)(Wp + (i << 2));
    }
    const int row = tid & 63, qd = tid >> 6;   // qd wave-uniform
    float4 rv[28];
    const float* orow = obuf + ((size_t)((b << 12) + hw0 + row)) * C_;
    #pragma unroll
    for (int i = 0; i < 28; ++i) rv[i] = *(const float4*)(orow + (i << 2));
    __syncthreads();
    #pragma unroll 1
    for (int dd = 0; dd < 28; ++dd) {
        const int d = qd * 28 + dd;
        const float* wrow = &wsh[d * C_];
        float acc = bp[d];
        #pragma unroll
        for (int i = 0; i < 28; ++i) {
            float4 wv = *(const float4*)(wrow + (i << 2));
            acc += rv[i].x * wv.x + rv[i].y * wv.y + rv[i].z * wv.z + rv[i].w * wv.w;
        }
        out[((size_t)(b * C_ + d) << 12) + hw0 + row] = acc;
    }
}

extern "C" void kernel_launch(void* const* d_in, const int* in_sizes, int n_in,
                              void* d_out, int out_size, void* d_ws, size_t ws_size,
                              hipStream_t stream) {
    const float* x     = (const float*)d_in[0];
    const float* Wqkv  = (const float*)d_in[1];
    const float* Wproj = (const float*)d_in[2];
    const float* bproj = (const float*)d_in[3];
    const int*   topk  = (const int*)d_in[4];
    float* out = (float*)d_out;
    char* ws = (char*)d_ws;
    float* qkv  = (float*)ws;                                // 88,080,384 B
    float* obuf = (float*)(ws + 88080384);                   // 29,360,128 B
    float* WT   = (float*)(ws + 88080384 + 29360128);        //    150,528 B
    wt_kernel<<<dim3((D3_ * C_ + 255) / 256), 256, 0, stream>>>(Wqkv, WT);
    qkv_kernel<<<dim3(64, 16), 256, 0, stream>>>(x, WT, qkv);
    attn_kernel<<<dim3(NWIN_, 16), 256, 0, stream>>>(qkv, topk, obuf);
    proj_kernel<<<dim3(64, 16), 256, 0, stream>>>(obuf, Wproj, bproj, out);
}

// Round 3
// 429.533 us; speedup vs baseline: 1.0972x; 1.0972x over previous
//
#include <hip/hip_runtime.h>
#include <hip/hip_bf16.h>
#include <cstdint>

#define B_ 16
#define C_ 112
#define HW_ 4096
#define HEADS_ 4
#define HD_ 28
#define NWIN_ 256
#define TOPK_ 128
#define D3_ 336
#define SCALE_ 0.18898223650461363f

// ---------------- kernel 0: transpose Wqkv (336x112) -> WqkvT (112x336) ----------------
__global__ void wt_kernel(const float* __restrict__ W, float* __restrict__ WT) {
    int idx = blockIdx.x * 256 + threadIdx.x;
    if (idx < D3_ * C_) {
        int d = idx / C_, c = idx % C_;
        WT[c * D3_ + d] = W[idx];
    }
}

// ---------------- kernel 1: qkv[b][hw][d] = sum_c x[b][c][hw] * Wqkv[d][c] ----------------
__global__ __launch_bounds__(256) void qkv_kernel(const float* __restrict__ x,
                                                  const float* __restrict__ WT,
                                                  float* __restrict__ qkv) {
    __shared__ float xs[C_][64];
    __shared__ float ws[C_][68];
    const int b = blockIdx.y;
    const int hw0 = blockIdx.x * 64;
    const int tid = threadIdx.x;
    for (int i = tid; i < C_ * 16; i += 256) {
        int c = i >> 4, j4 = (i & 15) << 2;
        *(float4*)&xs[c][j4] = *(const float4*)(x + (((size_t)b * C_ + c) << 12) + hw0 + j4);
    }
    const int tx = tid & 15;
    const int tj = tid >> 4;
    for (int dp = 0; dp < 6; ++dp) {
        const int d0 = dp << 6;
        __syncthreads();
        for (int i = tid; i < C_ * 16; i += 256) {
            int c = i >> 4, dl4 = (i & 15) << 2;
            float4 v = make_float4(0.f, 0.f, 0.f, 0.f);
            if (d0 + dl4 < D3_) v = *(const float4*)(WT + c * D3_ + d0 + dl4);
            *(float4*)&ws[c][dl4] = v;
        }
        __syncthreads();
        float acc[4][4];
        #pragma unroll
        for (int i = 0; i < 4; ++i)
            #pragma unroll
            for (int j = 0; j < 4; ++j) acc[i][j] = 0.f;
        #pragma unroll 4
        for (int c = 0; c < C_; ++c) {
            float4 wv = *(const float4*)&ws[c][tx << 2];
            float4 xv = *(const float4*)&xs[c][tj << 2];
            acc[0][0] += wv.x * xv.x; acc[0][1] += wv.x * xv.y; acc[0][2] += wv.x * xv.z; acc[0][3] += wv.x * xv.w;
            acc[1][0] += wv.y * xv.x; acc[1][1] += wv.y * xv.y; acc[1][2] += wv.y * xv.z; acc[1][3] += wv.y * xv.w;
            acc[2][0] += wv.z * xv.x; acc[2][1] += wv.z * xv.y; acc[2][2] += wv.z * xv.z; acc[2][3] += wv.z * xv.w;
            acc[3][0] += wv.w * xv.x; acc[3][1] += wv.w * xv.y; acc[3][2] += wv.w * xv.z; acc[3][3] += wv.w * xv.w;
        }
        const int dbase = d0 + (tx << 2);
        if (dbase < D3_) {
            #pragma unroll
            for (int j = 0; j < 4; ++j) {
                float4 o4 = make_float4(acc[0][j], acc[1][j], acc[2][j], acc[3][j]);
                *(float4*)(qkv + ((size_t)((b << 12) + hw0 + (tj << 2) + j)) * D3_ + dbase) = o4;
            }
        }
    }
}

// ---------------- kernel 2: windowed top-k attention (conflict-free LDS + async gather) ----------------
__global__ __launch_bounds__(256) void attn_kernel(const float* __restrict__ qkv,
                                                   const int* __restrict__ topk,
                                                   float* __restrict__ obuf) {
    __shared__ float qs[16][C_];        // scaled q rows (all heads)
    __shared__ float kT[HD_][TOPK_];    // K transposed [c][k]  (stride 128: writes/reads consecutive)
    __shared__ float vs[TOPK_][30];     // V rows, stride 30: scalar writes 2-way-free, float2 reads conflict-free
    __shared__ float ss[16][129];       // scores, stride 129: PV reads conflict-free
    __shared__ int idxs[TOPK_];
    const int b = blockIdx.y, w = blockIdx.x;
    const int wy = w >> 4, wx = w & 15;
    const int tid = threadIdx.x;
    if (tid < TOPK_) idxs[tid] = topk[w * TOPK_ + tid];
    for (int i = tid; i < 16 * 28; i += 256) {
        int q = i / 28, c4 = (i % 28) << 2;
        int hw = ((wy * 4 + (q >> 2)) << 6) + (wx << 2) + (q & 3);
        float4 v = *(const float4*)(qkv + ((size_t)((b << 12) + hw)) * D3_ + c4);
        v.x *= SCALE_; v.y *= SCALE_; v.z *= SCALE_; v.w *= SCALE_;
        *(float4*)&qs[q][c4] = v;
    }
    __syncthreads();   // qs + idxs ready
    const int gi = tid & 127, gsel = tid >> 7;   // 128 K-threads, 128 V-threads
    const float* gbase = qkv + ((size_t)((b << 12) + idxs[gi])) * D3_ + C_ + gsel * C_;
    float4 g0 = *(const float4*)(gbase);
    float4 g1 = *(const float4*)(gbase + 4);
    float4 g2 = *(const float4*)(gbase + 8);
    float4 g3 = *(const float4*)(gbase + 12);
    float4 g4 = *(const float4*)(gbase + 16);
    float4 g5 = *(const float4*)(gbase + 20);
    float4 g6 = *(const float4*)(gbase + 24);
    for (int h = 0; h < HEADS_; ++h) {
        if (h) __syncthreads();   // prior PV done reading kT/vs/ss
        if (gsel == 0) {          // conflict-free: gi consecutive across lanes
            kT[0][gi]  = g0.x; kT[1][gi]  = g0.y; kT[2][gi]  = g0.z; kT[3][gi]  = g0.w;
            kT[4][gi]  = g1.x; kT[5][gi]  = g1.y; kT[6][gi]  = g1.z; kT[7][gi]  = g1.w;
            kT[8][gi]  = g2.x; kT[9][gi]  = g2.y; kT[10][gi] = g2.z; kT[11][gi] = g2.w;
            kT[12][gi] = g3.x; kT[13][gi] = g3.y; kT[14][gi] = g3.z; kT[15][gi] = g3.w;
            kT[16][gi] = g4.x; kT[17][gi] = g4.y; kT[18][gi] = g4.z; kT[19][gi] = g4.w;
            kT[20][gi] = g5.x; kT[21][gi] = g5.y; kT[22][gi] = g5.z; kT[23][gi] = g5.w;
            kT[24][gi] = g6.x; kT[25][gi] = g6.y; kT[26][gi] = g6.z; kT[27][gi] = g6.w;
        } else {
            vs[gi][0]  = g0.x; vs[gi][1]  = g0.y; vs[gi][2]  = g0.z; vs[gi][3]  = g0.w;
            vs[gi][4]  = g1.x; vs[gi][5]  = g1.y; vs[gi][6]  = g1.z; vs[gi][7]  = g1.w;
            vs[gi][8]  = g2.x; vs[gi][9]  = g2.y; vs[gi][10] = g2.z; vs[gi][11] = g2.w;
            vs[gi][12] = g3.x; vs[gi][13] = g3.y; vs[gi][14] = g3.z; vs[gi][15] = g3.w;
            vs[gi][16] = g4.x; vs[gi][17] = g4.y; vs[gi][18] = g4.z; vs[gi][19] = g4.w;
            vs[gi][20] = g5.x; vs[gi][21] = g5.y; vs[gi][22] = g5.z; vs[gi][23] = g5.w;
            vs[gi][24] = g6.x; vs[gi][25] = g6.y; vs[gi][26] = g6.z; vs[gi][27] = g6.w;
        }
        __syncthreads();
        // ---- scores ----
        {
            const int k = tid & 127, qh = tid >> 7;
            float kc[28];
            #pragma unroll
            for (int c = 0; c < 28; ++c) kc[c] = kT[c][k];
            #pragma unroll
            for (int qi = 0; qi < 8; ++qi) {
                const int q = qh * 8 + qi;
                const float* qrow = &qs[q][h * HD_];
                float s = 0.f;
                #pragma unroll
                for (int c4 = 0; c4 < HD_; c4 += 4) {
                    float4 qv = *(const float4*)(qrow + c4);
                    s += qv.x * kc[c4] + qv.y * kc[c4 + 1] + qv.z * kc[c4 + 2] + qv.w * kc[c4 + 3];
                }
                ss[q][k] = s;
            }
        }
        __syncthreads();
        // ---- softmax (16 lanes per row) ----
        {
            const int q = tid >> 4, l = tid & 15;
            float vals[8];
            float m = -1e30f;
            #pragma unroll
            for (int j = 0; j < 8; ++j) { vals[j] = ss[q][l + (j << 4)]; m = fmaxf(m, vals[j]); }
            #pragma unroll
            for (int sft = 1; sft < 16; sft <<= 1) m = fmaxf(m, __shfl_xor(m, sft, 64));
            float sum = 0.f;
            #pragma unroll
            for (int j = 0; j < 8; ++j) { vals[j] = __expf(vals[j] - m); sum += vals[j]; }
            #pragma unroll
            for (int sft = 1; sft < 16; sft <<= 1) sum += __shfl_xor(sum, sft, 64);
            const float inv = 1.f / sum;
            #pragma unroll
            for (int j = 0; j < 8; ++j) ss[q][l + (j << 4)] = vals[j] * inv;
        }
        __syncthreads();
        // ---- issue next head's gather while PV runs (T14 async-stage) ----
        if (h < HEADS_ - 1) {
            const float* gb = gbase + (h + 1) * HD_;
            g0 = *(const float4*)(gb);
            g1 = *(const float4*)(gb + 4);
            g2 = *(const float4*)(gb + 8);
            g3 = *(const float4*)(gb + 12);
            g4 = *(const float4*)(gb + 16);
            g5 = *(const float4*)(gb + 20);
            g6 = *(const float4*)(gb + 24);
        }
        // ---- PV: thread = (q, d-pair), direct global write ----
        {
            const int q = tid & 15, dg = tid >> 4;
            if (dg < 14) {
                float a0 = 0.f, a1 = 0.f;
                #pragma unroll 8
                for (int k = 0; k < TOPK_; ++k) {
                    float2 v2 = *(const float2*)&vs[k][dg << 1];
                    float p = ss[q][k];
                    a0 += p * v2.x;
                    a1 += p * v2.y;
                }
                const int hw = ((wy * 4 + (q >> 2)) << 6) + (wx << 2) + (q & 3);
                float2 o2 = make_float2(a0, a1);
                *(float2*)(obuf + ((size_t)((b << 12) + hw)) * C_ + h * HD_ + (dg << 1)) = o2;
            }
        }
    }
}

// ---------------- kernel 3: out[b][d][hw] = sum_c o[b][hw][c]*Wproj[d][c] + bproj[d] ----------------
__global__ __launch_bounds__(256) void proj_kernel(const float* __restrict__ obuf,
                                                   const float* __restrict__ Wp,
                                                   const float* __restrict__ bp,
                                                   float* __restrict__ out) {
    __shared__ float wsh[C_ * C_];
    const int b = blockIdx.y;
    const int hw0 = blockIdx.x * 64;
    const int tid = threadIdx.x;
    for (int i = tid; i < C_ * C_ / 4; i += 256) {
        *(float4*)&wsh[i << 2] = *(const float4*)(Wp + (i << 2));
    }
    const int row = tid & 63, qd = tid >> 6;
    float4 rv[28];
    const float* orow = obuf + ((size_t)((b << 12) + hw0 + row)) * C_;
    #pragma unroll
    for (int i = 0; i < 28; ++i) rv[i] = *(const float4*)(orow + (i << 2));
    __syncthreads();
    #pragma unroll 1
    for (int dd = 0; dd < 28; ++dd) {
        const int d = qd * 28 + dd;
        const float* wrow = &wsh[d * C_];
        float acc = bp[d];
        #pragma unroll
        for (int i = 0; i < 28; ++i) {
            float4 wv = *(const float4*)(wrow + (i << 2));
            acc += rv[i].x * wv.x + rv[i].y * wv.y + rv[i].z * wv.z + rv[i].w * wv.w;
        }
        out[((size_t)(b * C_ + d) << 12) + hw0 + row] = acc;
    }
}

extern "C" void kernel_launch(void* const* d_in, const int* in_sizes, int n_in,
                              void* d_out, int out_size, void* d_ws, size_t ws_size,
                              hipStream_t stream) {
    const float* x     = (const float*)d_in[0];
    const float* Wqkv  = (const float*)d_in[1];
    const float* Wproj = (const float*)d_in[2];
    const float* bproj = (const float*)d_in[3];
    const int*   topk  = (const int*)d_in[4];
    float* out = (float*)d_out;
    char* ws = (char*)d_ws;
    float* qkv  = (float*)ws;                                // 88,080,384 B
    float* obuf = (float*)(ws + 88080384);                   // 29,360,128 B
    float* WT   = (float*)(ws + 88080384 + 29360128);        //    150,528 B
    wt_kernel<<<dim3((D3_ * C_ + 255) / 256), 256, 0, stream>>>(Wqkv, WT);
    qkv_kernel<<<dim3(64, 16), 256, 0, stream>>>(x, WT, qkv);
    attn_kernel<<<dim3(NWIN_, 16), 256, 0, stream>>>(qkv, topk, obuf);
    proj_kernel<<<dim3(64, 16), 256, 0, stream>>>(obuf, Wproj, bproj, out);
}

// Round 4
// 363.345 us; speedup vs baseline: 1.2970x; 1.1822x over previous
//
#include <hip/hip_runtime.h>
#include <hip/hip_bf16.h>
#include <cstdint>

#define B_ 16
#define C_ 112
#define HW_ 4096
#define HEADS_ 4
#define HD_ 28
#define NWIN_ 256
#define TOPK_ 128
#define D3_ 336
#define SCALE_ 0.18898223650461363f

__device__ inline unsigned cvtpk(float a, float b) {
    unsigned r;
    asm("v_cvt_pk_bf16_f32 %0, %1, %2" : "=v"(r) : "v"(a), "v"(b));
    return r;   // lo16 = bf16(a), hi16 = bf16(b)
}
__device__ inline float bf16lo(unsigned u) { return __uint_as_float(u << 16); }
__device__ inline float bf16hi(unsigned u) { return __uint_as_float(u & 0xFFFF0000u); }

// ---------------- kernel 0: transpose Wqkv (336x112) -> WqkvT (112x336) ----------------
__global__ void wt_kernel(const float* __restrict__ W, float* __restrict__ WT) {
    int idx = blockIdx.x * 256 + threadIdx.x;
    if (idx < D3_ * C_) {
        int d = idx / C_, c = idx % C_;
        WT[c * D3_ + d] = W[idx];
    }
}

// ---------------- kernel 1: qkv[b][hw][d] = sum_c x[b][c][hw] * Wqkv[d][c] ----------------
// 128hw x 128d tile, 8x8 per thread, K chunked by 28. 4 b128 LDS reads / 64 FMA.
__global__ __launch_bounds__(256) void qkv_kernel(const float* __restrict__ x,
                                                  const float* __restrict__ WT,
                                                  float* __restrict__ qkv) {
    __shared__ float xs[28][128];
    __shared__ float ws[28][128];
    const int b = blockIdx.z;
    const int hw0 = blockIdx.x * 128;
    const int d0 = blockIdx.y * 128;
    const int tid = threadIdx.x;
    const int tx = tid & 15;   // hw group (8 rows each)
    const int ty = tid >> 4;   // d group (8 cols each)
    float acc[8][8] = {};
    for (int c0 = 0; c0 < C_; c0 += 28) {
        __syncthreads();
        for (int i = tid; i < 28 * 32; i += 256) {
            int c = i >> 5, j4 = (i & 31) << 2;
            *(float4*)&xs[c][j4] = *(const float4*)(x + (((size_t)b * C_ + c0 + c) << 12) + hw0 + j4);
        }
        for (int i = tid; i < 28 * 32; i += 256) {
            int c = i >> 5, d4 = (i & 31) << 2;
            float4 v = make_float4(0.f, 0.f, 0.f, 0.f);
            if (d0 + d4 < D3_) v = *(const float4*)(WT + (size_t)(c0 + c) * D3_ + d0 + d4);
            *(float4*)&ws[c][d4] = v;
        }
        __syncthreads();
        #pragma unroll 4
        for (int c = 0; c < 28; ++c) {
            float xv[8], wv[8];
            *(float4*)&xv[0] = *(float4*)&xs[c][tx << 3];
            *(float4*)&xv[4] = *(float4*)&xs[c][(tx << 3) + 4];
            *(float4*)&wv[0] = *(float4*)&ws[c][ty << 3];
            *(float4*)&wv[4] = *(float4*)&ws[c][(ty << 3) + 4];
            #pragma unroll
            for (int i = 0; i < 8; ++i)
                #pragma unroll
                for (int j = 0; j < 8; ++j) acc[i][j] += xv[i] * wv[j];
        }
    }
    const int dbase = d0 + (ty << 3);
    if (dbase < D3_) {   // 336 % 8 == 0 -> whole 8-col group valid or not
        #pragma unroll
        for (int i = 0; i < 8; ++i) {
            float* dst = qkv + (size_t)((b << 12) + hw0 + (tx << 3) + i) * D3_ + dbase;
            *(float4*)dst = make_float4(acc[i][0], acc[i][1], acc[i][2], acc[i][3]);
            *(float4*)(dst + 4) = make_float4(acc[i][4], acc[i][5], acc[i][6], acc[i][7]);
        }
    }
}

// ---------------- kernel 2: windowed top-k attention (bf16 K/V in LDS) ----------------
__global__ __launch_bounds__(256) void attn_kernel(const float* __restrict__ qkv,
                                                   const int* __restrict__ topk,
                                                   float* __restrict__ obuf) {
    __shared__ float qs[16][C_];              // scaled q rows, fp32 (broadcast reads)
    __shared__ unsigned kT2[14][TOPK_];       // K bf16-pairs, transposed [c/2][k]
    __shared__ uint2 vs4[7][TOPK_];           // V bf16-quads, transposed [d/4][k]
    __shared__ float ss[16][129];             // scores (stride 129: conflict-free)
    __shared__ int idxs[TOPK_];
    const int b = blockIdx.y, w = blockIdx.x;
    const int wy = w >> 4, wx = w & 15;
    const int tid = threadIdx.x;
    if (tid < TOPK_) idxs[tid] = topk[w * TOPK_ + tid];
    for (int i = tid; i < 16 * 28; i += 256) {
        int q = i / 28, c4 = (i % 28) << 2;
        int hw = ((wy * 4 + (q >> 2)) << 6) + (wx << 2) + (q & 3);
        float4 v = *(const float4*)(qkv + ((size_t)((b << 12) + hw)) * D3_ + c4);
        v.x *= SCALE_; v.y *= SCALE_; v.z *= SCALE_; v.w *= SCALE_;
        *(float4*)&qs[q][c4] = v;
    }
    __syncthreads();   // qs + idxs ready
    const int gi = tid & 127, gsel = tid >> 7;   // 128 K-threads, 128 V-threads
    const float* gbase = qkv + ((size_t)((b << 12) + idxs[gi])) * D3_ + C_ + gsel * C_;
    float4 g0 = *(const float4*)(gbase);
    float4 g1 = *(const float4*)(gbase + 4);
    float4 g2 = *(const float4*)(gbase + 8);
    float4 g3 = *(const float4*)(gbase + 12);
    float4 g4 = *(const float4*)(gbase + 16);
    float4 g5 = *(const float4*)(gbase + 20);
    float4 g6 = *(const float4*)(gbase + 24);
    for (int h = 0; h < HEADS_; ++h) {
        if (h) __syncthreads();   // prior PV done reading kT2/vs4/ss
        {   // pack 28 floats -> 14 bf16-pairs and stage
            unsigned p0  = cvtpk(g0.x, g0.y), p1  = cvtpk(g0.z, g0.w);
            unsigned p2  = cvtpk(g1.x, g1.y), p3  = cvtpk(g1.z, g1.w);
            unsigned p4  = cvtpk(g2.x, g2.y), p5  = cvtpk(g2.z, g2.w);
            unsigned p6  = cvtpk(g3.x, g3.y), p7  = cvtpk(g3.z, g3.w);
            unsigned p8  = cvtpk(g4.x, g4.y), p9  = cvtpk(g4.z, g4.w);
            unsigned p10 = cvtpk(g5.x, g5.y), p11 = cvtpk(g5.z, g5.w);
            unsigned p12 = cvtpk(g6.x, g6.y), p13 = cvtpk(g6.z, g6.w);
            if (gsel == 0) {   // K: [c2][k], lanes k-consecutive -> conflict-free
                kT2[0][gi] = p0;  kT2[1][gi] = p1;  kT2[2][gi] = p2;  kT2[3][gi] = p3;
                kT2[4][gi] = p4;  kT2[5][gi] = p5;  kT2[6][gi] = p6;  kT2[7][gi] = p7;
                kT2[8][gi] = p8;  kT2[9][gi] = p9;  kT2[10][gi] = p10; kT2[11][gi] = p11;
                kT2[12][gi] = p12; kT2[13][gi] = p13;
            } else {           // V: [d4][k] uint2, lanes k-consecutive b64 -> conflict-free
                vs4[0][gi] = make_uint2(p0, p1);
                vs4[1][gi] = make_uint2(p2, p3);
                vs4[2][gi] = make_uint2(p4, p5);
                vs4[3][gi] = make_uint2(p6, p7);
                vs4[4][gi] = make_uint2(p8, p9);
                vs4[5][gi] = make_uint2(p10, p11);
                vs4[6][gi] = make_uint2(p12, p13);
            }
        }
        __syncthreads();
        // ---- scores: thread = (k, q-half); K column unpacked to regs ----
        {
            const int k = tid & 127, qh = tid >> 7;
            float kc[28];
            #pragma unroll
            for (int c2 = 0; c2 < 14; ++c2) {
                unsigned u = kT2[c2][k];
                kc[2 * c2] = bf16lo(u);
                kc[2 * c2 + 1] = bf16hi(u);
            }
            const int hq = h * HD_;
            #pragma unroll
            for (int qi = 0; qi < 8; ++qi) {
                const int q = qh * 8 + qi;
                const float* qrow = &qs[q][hq];
                float s = 0.f;
                #pragma unroll
                for (int c4 = 0; c4 < HD_; c4 += 4) {
                    float4 qv = *(const float4*)(qrow + c4);
                    s += qv.x * kc[c4] + qv.y * kc[c4 + 1] + qv.z * kc[c4 + 2] + qv.w * kc[c4 + 3];
                }
                ss[q][k] = s;
            }
        }
        __syncthreads();
        // ---- softmax (16 lanes per row) ----
        {
            const int q = tid >> 4, l = tid & 15;
            float vals[8];
            float m = -1e30f;
            #pragma unroll
            for (int j = 0; j < 8; ++j) { vals[j] = ss[q][l + (j << 4)]; m = fmaxf(m, vals[j]); }
            #pragma unroll
            for (int sft = 1; sft < 16; sft <<= 1) m = fmaxf(m, __shfl_xor(m, sft, 64));
            float sum = 0.f;
            #pragma unroll
            for (int j = 0; j < 8; ++j) { vals[j] = __expf(vals[j] - m); sum += vals[j]; }
            #pragma unroll
            for (int sft = 1; sft < 16; sft <<= 1) sum += __shfl_xor(sum, sft, 64);
            const float inv = 1.f / sum;
            #pragma unroll
            for (int j = 0; j < 8; ++j) ss[q][l + (j << 4)] = vals[j] * inv;
        }
        __syncthreads();
        // ---- prefetch next head's gather during PV (T14 async-stage) ----
        if (h < HEADS_ - 1) {
            const float* gb = gbase + (h + 1) * HD_;
            g0 = *(const float4*)(gb);
            g1 = *(const float4*)(gb + 4);
            g2 = *(const float4*)(gb + 8);
            g3 = *(const float4*)(gb + 12);
            g4 = *(const float4*)(gb + 16);
            g5 = *(const float4*)(gb + 20);
            g6 = *(const float4*)(gb + 24);
        }
        // ---- PV: thread = (q, d-quad); 1 b64 + 1 b32 per 4 FMA ----
        {
            const int q = tid & 15, dg = tid >> 4;
            if (dg < 7) {
                float a0 = 0.f, a1 = 0.f, a2 = 0.f, a3 = 0.f;
                #pragma unroll 8
                for (int k = 0; k < TOPK_; ++k) {
                    uint2 vv = vs4[dg][k];
                    float p = ss[q][k];
                    a0 += p * bf16lo(vv.x);
                    a1 += p * bf16hi(vv.x);
                    a2 += p * bf16lo(vv.y);
                    a3 += p * bf16hi(vv.y);
                }
                const int hw = ((wy * 4 + (q >> 2)) << 6) + (wx << 2) + (q & 3);
                *(float4*)(obuf + ((size_t)((b << 12) + hw)) * C_ + h * HD_ + (dg << 2)) =
                    make_float4(a0, a1, a2, a3);
            }
        }
    }
}

// ---------------- kernel 3: out[b][d][hw] = sum_c o[b][hw][c]*Wproj[d][c] + bproj[d] ----------------
__global__ __launch_bounds__(256) void proj_kernel(const float* __restrict__ obuf,
                                                   const float* __restrict__ Wp,
                                                   const float* __restrict__ bp,
                                                   float* __restrict__ out) {
    __shared__ float wsh[C_ * C_];
    const int b = blockIdx.y;
    const int hw0 = blockIdx.x * 64;
    const int tid = threadIdx.x;
    for (int i = tid; i < C_ * C_ / 4; i += 256) {
        *(float4*)&wsh[i << 2] = *(const float4*)(Wp + (i << 2));
    }
    const int row = tid & 63, qd = tid >> 6;
    float4 rv[28];
    const float* orow = obuf + ((size_t)((b << 12) + hw0 + row)) * C_;
    #pragma unroll
    for (int i = 0; i < 28; ++i) rv[i] = *(const float4*)(orow + (i << 2));
    __syncthreads();
    #pragma unroll 1
    for (int dd = 0; dd < 28; ++dd) {
        const int d = qd * 28 + dd;
        const float* wrow = &wsh[d * C_];
        float acc = bp[d];
        #pragma unroll
        for (int i = 0; i < 28; ++i) {
            float4 wv = *(const float4*)(wrow + (i << 2));
            acc += rv[i].x * wv.x + rv[i].y * wv.y + rv[i].z * wv.z + rv[i].w * wv.w;
        }
        out[((size_t)(b * C_ + d) << 12) + hw0 + row] = acc;
    }
}

extern "C" void kernel_launch(void* const* d_in, const int* in_sizes, int n_in,
                              void* d_out, int out_size, void* d_ws, size_t ws_size,
                              hipStream_t stream) {
    const float* x     = (const float*)d_in[0];
    const float* Wqkv  = (const float*)d_in[1];
    const float* Wproj = (const float*)d_in[2];
    const float* bproj = (const float*)d_in[3];
    const int*   topk  = (const int*)d_in[4];
    float* out = (float*)d_out;
    char* ws = (char*)d_ws;
    float* qkv  = (float*)ws;                                // 88,080,384 B
    float* obuf = (float*)(ws + 88080384);                   // 29,360,128 B
    float* WT   = (float*)(ws + 88080384 + 29360128);        //    150,528 B
    wt_kernel<<<dim3((D3_ * C_ + 255) / 256), 256, 0, stream>>>(Wqkv, WT);
    qkv_kernel<<<dim3(32, 3, 16), 256, 0, stream>>>(x, WT, qkv);
    attn_kernel<<<dim3(NWIN_, 16), 256, 0, stream>>>(qkv, topk, obuf);
    proj_kernel<<<dim3(64, 16), 256, 0, stream>>>(obuf, Wproj, bproj, out);
}

// Round 5
// 299.708 us; speedup vs baseline: 1.5724x; 1.2123x over previous
//
#include <hip/hip_runtime.h>
#include <hip/hip_bf16.h>
#include <cstdint>

#define B_ 16
#define C_ 112
#define HW_ 4096
#define HEADS_ 4
#define HD_ 28
#define NWIN_ 256
#define TOPK_ 128
#define D3_ 336
#define SCALE_ 0.18898223650461363f

__device__ inline unsigned cvtpk(float a, float b) {
    unsigned r;
    asm("v_cvt_pk_bf16_f32 %0, %1, %2" : "=v"(r) : "v"(a), "v"(b));
    return r;   // lo16 = bf16(a), hi16 = bf16(b)
}
__device__ inline float bf16lo(unsigned u) { return __uint_as_float(u << 16); }
__device__ inline float bf16hi(unsigned u) { return __uint_as_float(u & 0xFFFF0000u); }

// ---------------- kernel 0: transpose Wqkv (336x112)->WT (112x336) and Wproj (112x112)->WTp (112x112) ----------------
__global__ void wt_kernel(const float* __restrict__ W, const float* __restrict__ Wp,
                          float* __restrict__ WT, float* __restrict__ WTp) {
    int idx = blockIdx.x * 256 + threadIdx.x;
    if (idx < D3_ * C_) {
        int d = idx / C_, c = idx % C_;
        WT[c * D3_ + d] = W[idx];
    } else {
        int j = idx - D3_ * C_;
        if (j < C_ * C_) {
            int d = j / C_, c = j % C_;
            WTp[c * C_ + d] = Wp[j];
        }
    }
}

// ---------------- kernel 1: qkv[b][hw][d] = sum_c x[b][c][hw] * Wqkv[d][c] ----------------
// 128hw x 128d tile, 8x8 per thread, K chunked by 28. 4 b128 LDS reads / 64 FMA.
__global__ __launch_bounds__(256) void qkv_kernel(const float* __restrict__ x,
                                                  const float* __restrict__ WT,
                                                  float* __restrict__ qkv) {
    __shared__ float xs[28][128];
    __shared__ float ws[28][128];
    const int b = blockIdx.z;
    const int hw0 = blockIdx.x * 128;
    const int d0 = blockIdx.y * 128;
    const int tid = threadIdx.x;
    const int tx = tid & 15;   // hw group (8 rows each)
    const int ty = tid >> 4;   // d group (8 cols each)
    float acc[8][8] = {};
    for (int c0 = 0; c0 < C_; c0 += 28) {
        __syncthreads();
        for (int i = tid; i < 28 * 32; i += 256) {
            int c = i >> 5, j4 = (i & 31) << 2;
            *(float4*)&xs[c][j4] = *(const float4*)(x + (((size_t)b * C_ + c0 + c) << 12) + hw0 + j4);
        }
        for (int i = tid; i < 28 * 32; i += 256) {
            int c = i >> 5, d4 = (i & 31) << 2;
            float4 v = make_float4(0.f, 0.f, 0.f, 0.f);
            if (d0 + d4 < D3_) v = *(const float4*)(WT + (size_t)(c0 + c) * D3_ + d0 + d4);
            *(float4*)&ws[c][d4] = v;
        }
        __syncthreads();
        #pragma unroll 4
        for (int c = 0; c < 28; ++c) {
            float xv[8], wv[8];
            *(float4*)&xv[0] = *(float4*)&xs[c][tx << 3];
            *(float4*)&xv[4] = *(float4*)&xs[c][(tx << 3) + 4];
            *(float4*)&wv[0] = *(float4*)&ws[c][ty << 3];
            *(float4*)&wv[4] = *(float4*)&ws[c][(ty << 3) + 4];
            #pragma unroll
            for (int i = 0; i < 8; ++i)
                #pragma unroll
                for (int j = 0; j < 8; ++j) acc[i][j] += xv[i] * wv[j];
        }
    }
    const int dbase = d0 + (ty << 3);
    if (dbase < D3_) {
        #pragma unroll
        for (int i = 0; i < 8; ++i) {
            float* dst = qkv + (size_t)((b << 12) + hw0 + (tx << 3) + i) * D3_ + dbase;
            *(float4*)dst = make_float4(acc[i][0], acc[i][1], acc[i][2], acc[i][3]);
            *(float4*)(dst + 4) = make_float4(acc[i][4], acc[i][5], acc[i][6], acc[i][7]);
        }
    }
}

// ---------------- kernel 2: windowed top-k attention (bf16 K/V in LDS) ----------------
__global__ __launch_bounds__(256) void attn_kernel(const float* __restrict__ qkv,
                                                   const int* __restrict__ topk,
                                                   float* __restrict__ obuf) {
    __shared__ float qs[16][C_];              // scaled q rows, fp32 (broadcast reads)
    __shared__ unsigned kT2[14][TOPK_];       // K bf16-pairs, transposed [c/2][k]
    __shared__ uint2 vs4[7][129];             // V bf16-quads [d/4][k], pad 129: dg-rows hit disjoint bank-pairs
    __shared__ float ss[16][129];             // scores (stride 129: conflict-free)
    __shared__ int idxs[TOPK_];
    const int b = blockIdx.y, w = blockIdx.x;
    const int wy = w >> 4, wx = w & 15;
    const int tid = threadIdx.x;
    if (tid < TOPK_) idxs[tid] = topk[w * TOPK_ + tid];
    for (int i = tid; i < 16 * 28; i += 256) {
        int q = i / 28, c4 = (i % 28) << 2;
        int hw = ((wy * 4 + (q >> 2)) << 6) + (wx << 2) + (q & 3);
        float4 v = *(const float4*)(qkv + ((size_t)((b << 12) + hw)) * D3_ + c4);
        v.x *= SCALE_; v.y *= SCALE_; v.z *= SCALE_; v.w *= SCALE_;
        *(float4*)&qs[q][c4] = v;
    }
    __syncthreads();   // qs + idxs ready
    const int gi = tid & 127, gsel = tid >> 7;   // 128 K-threads, 128 V-threads
    const float* gbase = qkv + ((size_t)((b << 12) + idxs[gi])) * D3_ + C_ + gsel * C_;
    float4 g0 = *(const float4*)(gbase);
    float4 g1 = *(const float4*)(gbase + 4);
    float4 g2 = *(const float4*)(gbase + 8);
    float4 g3 = *(const float4*)(gbase + 12);
    float4 g4 = *(const float4*)(gbase + 16);
    float4 g5 = *(const float4*)(gbase + 20);
    float4 g6 = *(const float4*)(gbase + 24);
    for (int h = 0; h < HEADS_; ++h) {
        if (h) __syncthreads();   // prior PV done reading kT2/vs4/ss
        {   // pack 28 floats -> 14 bf16-pairs and stage
            unsigned p0  = cvtpk(g0.x, g0.y), p1  = cvtpk(g0.z, g0.w);
            unsigned p2  = cvtpk(g1.x, g1.y), p3  = cvtpk(g1.z, g1.w);
            unsigned p4  = cvtpk(g2.x, g2.y), p5  = cvtpk(g2.z, g2.w);
            unsigned p6  = cvtpk(g3.x, g3.y), p7  = cvtpk(g3.z, g3.w);
            unsigned p8  = cvtpk(g4.x, g4.y), p9  = cvtpk(g4.z, g4.w);
            unsigned p10 = cvtpk(g5.x, g5.y), p11 = cvtpk(g5.z, g5.w);
            unsigned p12 = cvtpk(g6.x, g6.y), p13 = cvtpk(g6.z, g6.w);
            if (gsel == 0) {
                kT2[0][gi] = p0;  kT2[1][gi] = p1;  kT2[2][gi] = p2;  kT2[3][gi] = p3;
                kT2[4][gi] = p4;  kT2[5][gi] = p5;  kT2[6][gi] = p6;  kT2[7][gi] = p7;
                kT2[8][gi] = p8;  kT2[9][gi] = p9;  kT2[10][gi] = p10; kT2[11][gi] = p11;
                kT2[12][gi] = p12; kT2[13][gi] = p13;
            } else {
                vs4[0][gi] = make_uint2(p0, p1);
                vs4[1][gi] = make_uint2(p2, p3);
                vs4[2][gi] = make_uint2(p4, p5);
                vs4[3][gi] = make_uint2(p6, p7);
                vs4[4][gi] = make_uint2(p8, p9);
                vs4[5][gi] = make_uint2(p10, p11);
                vs4[6][gi] = make_uint2(p12, p13);
            }
        }
        __syncthreads();
        // ---- scores: thread = (k, q-half); K column unpacked to regs ----
        {
            const int k = tid & 127, qh = tid >> 7;
            float kc[28];
            #pragma unroll
            for (int c2 = 0; c2 < 14; ++c2) {
                unsigned u = kT2[c2][k];
                kc[2 * c2] = bf16lo(u);
                kc[2 * c2 + 1] = bf16hi(u);
            }
            const int hq = h * HD_;
            #pragma unroll
            for (int qi = 0; qi < 8; ++qi) {
                const int q = qh * 8 + qi;
                const float* qrow = &qs[q][hq];
                float s = 0.f;
                #pragma unroll
                for (int c4 = 0; c4 < HD_; c4 += 4) {
                    float4 qv = *(const float4*)(qrow + c4);
                    s += qv.x * kc[c4] + qv.y * kc[c4 + 1] + qv.z * kc[c4 + 2] + qv.w * kc[c4 + 3];
                }
                ss[q][k] = s;
            }
        }
        __syncthreads();
        // ---- softmax (16 lanes per row) ----
        {
            const int q = tid >> 4, l = tid & 15;
            float vals[8];
            float m = -1e30f;
            #pragma unroll
            for (int j = 0; j < 8; ++j) { vals[j] = ss[q][l + (j << 4)]; m = fmaxf(m, vals[j]); }
            #pragma unroll
            for (int sft = 1; sft < 16; sft <<= 1) m = fmaxf(m, __shfl_xor(m, sft, 64));
            float sum = 0.f;
            #pragma unroll
            for (int j = 0; j < 8; ++j) { vals[j] = __expf(vals[j] - m); sum += vals[j]; }
            #pragma unroll
            for (int sft = 1; sft < 16; sft <<= 1) sum += __shfl_xor(sum, sft, 64);
            const float inv = 1.f / sum;
            #pragma unroll
            for (int j = 0; j < 8; ++j) ss[q][l + (j << 4)] = vals[j] * inv;
        }
        __syncthreads();
        // ---- prefetch next head's gather during PV (T14 async-stage) ----
        if (h < HEADS_ - 1) {
            const float* gb = gbase + (h + 1) * HD_;
            g0 = *(const float4*)(gb);
            g1 = *(const float4*)(gb + 4);
            g2 = *(const float4*)(gb + 8);
            g3 = *(const float4*)(gb + 12);
            g4 = *(const float4*)(gb + 16);
            g5 = *(const float4*)(gb + 20);
            g6 = *(const float4*)(gb + 24);
        }
        // ---- PV: thread = (q, d-quad) ----
        {
            const int q = tid & 15, dg = tid >> 4;
            if (dg < 7) {
                float a0 = 0.f, a1 = 0.f, a2 = 0.f, a3 = 0.f;
                #pragma unroll 8
                for (int k = 0; k < TOPK_; ++k) {
                    uint2 vv = vs4[dg][k];
                    float p = ss[q][k];
                    a0 += p * bf16lo(vv.x);
                    a1 += p * bf16hi(vv.x);
                    a2 += p * bf16lo(vv.y);
                    a3 += p * bf16hi(vv.y);
                }
                const int hw = ((wy * 4 + (q >> 2)) << 6) + (wx << 2) + (q & 3);
                *(float4*)(obuf + ((size_t)((b << 12) + hw)) * C_ + h * HD_ + (dg << 2)) =
                    make_float4(a0, a1, a2, a3);
            }
        }
    }
}

// ---------------- kernel 3: out[b][d][hw] = sum_c o[b][hw][c]*Wproj[d][c] + bproj[d] ----------------
// 128hw x 112d tile, K chunked by 28, 8x8 per thread (ty<14 active). 4 b128 LDS reads / 64 FMA.
__global__ __launch_bounds__(256) void proj_kernel(const float* __restrict__ obuf,
                                                   const float* __restrict__ WTp,
                                                   const float* __restrict__ bp,
                                                   float* __restrict__ out) {
    __shared__ float os_t[28][128];   // o transposed [c][hw]
    __shared__ float ws[28][116];     // WprojT [c][d], pad 116
    const int b = blockIdx.y;
    const int hw0 = blockIdx.x * 128;
    const int tid = threadIdx.x;
    const int tx = tid & 15;   // hw group (8 each)
    const int ty = tid >> 4;   // d group (8 each, ty<14 active)
    float acc[8][8] = {};
    for (int c0 = 0; c0 < C_; c0 += 28) {
        __syncthreads();
        // stage o tile transposed: read float4 along c (coalesced), scatter to [c][hw]
        for (int i = tid; i < 896; i += 256) {
            int hw = i / 7, c4 = (i % 7) << 2;
            float4 v = *(const float4*)(obuf + ((size_t)((b << 12) + hw0 + hw)) * C_ + c0 + c4);
            os_t[c4][hw] = v.x; os_t[c4 + 1][hw] = v.y; os_t[c4 + 2][hw] = v.z; os_t[c4 + 3][hw] = v.w;
        }
        // stage W tile: WTp row-major [c][d], clean b128
        for (int i = tid; i < 784; i += 256) {
            int c = i / 28, d4 = (i % 28) << 2;
            *(float4*)&ws[c][d4] = *(const float4*)(WTp + (size_t)(c0 + c) * C_ + d4);
        }
        __syncthreads();
        if (ty < 14) {
            #pragma unroll 4
            for (int c = 0; c < 28; ++c) {
                float xv[8], wv[8];
                *(float4*)&xv[0] = *(float4*)&os_t[c][tx << 3];
                *(float4*)&xv[4] = *(float4*)&os_t[c][(tx << 3) + 4];
                *(float4*)&wv[0] = *(float4*)&ws[c][ty << 3];
                *(float4*)&wv[4] = *(float4*)&ws[c][(ty << 3) + 4];
                #pragma unroll
                for (int i = 0; i < 8; ++i)
                    #pragma unroll
                    for (int j = 0; j < 8; ++j) acc[i][j] += xv[i] * wv[j];
            }
        }
    }
    if (ty < 14) {
        #pragma unroll
        for (int j = 0; j < 8; ++j) {
            const int d = (ty << 3) + j;
            const float bv = bp[d];
            float* dst = out + ((size_t)(b * C_ + d) << 12) + hw0 + (tx << 3);
            *(float4*)dst = make_float4(acc[0][j] + bv, acc[1][j] + bv, acc[2][j] + bv, acc[3][j] + bv);
            *(float4*)(dst + 4) = make_float4(acc[4][j] + bv, acc[5][j] + bv, acc[6][j] + bv, acc[7][j] + bv);
        }
    }
}

extern "C" void kernel_launch(void* const* d_in, const int* in_sizes, int n_in,
                              void* d_out, int out_size, void* d_ws, size_t ws_size,
                              hipStream_t stream) {
    const float* x     = (const float*)d_in[0];
    const float* Wqkv  = (const float*)d_in[1];
    const float* Wproj = (const float*)d_in[2];
    const float* bproj = (const float*)d_in[3];
    const int*   topk  = (const int*)d_in[4];
    float* out = (float*)d_out;
    char* ws = (char*)d_ws;
    float* qkv  = (float*)ws;                                // 88,080,384 B
    float* obuf = (float*)(ws + 88080384);                   // 29,360,128 B
    float* WT   = (float*)(ws + 88080384 + 29360128);        //    150,528 B
    float* WTp  = (float*)(ws + 88080384 + 29360128 + 150528); //   50,176 B
    wt_kernel<<<dim3((D3_ * C_ + C_ * C_ + 255) / 256), 256, 0, stream>>>(Wqkv, Wproj, WT, WTp);
    qkv_kernel<<<dim3(32, 3, 16), 256, 0, stream>>>(x, WT, qkv);
    attn_kernel<<<dim3(NWIN_, 16), 256, 0, stream>>>(qkv, topk, obuf);
    proj_kernel<<<dim3(32, 16), 256, 0, stream>>>(obuf, WTp, bproj, out);
}

// Round 6
// 244.276 us; speedup vs baseline: 1.9293x; 1.2269x over previous
//
#include <hip/hip_runtime.h>
#include <hip/hip_bf16.h>
#include <cstdint>

#define B_ 16
#define C_ 112
#define HW_ 4096
#define HEADS_ 4
#define HD_ 28
#define NWIN_ 256
#define TOPK_ 128
#define D3_ 336
#define SCALE_ 0.18898223650461363f

typedef __attribute__((ext_vector_type(4))) float f32x4;
typedef __attribute__((ext_vector_type(8))) short short8;

union Frag { unsigned u[4]; uint4 u4; short8 s; };

__device__ inline unsigned cvtpk(float a, float b) {
    unsigned r;
    asm("v_cvt_pk_bf16_f32 %0, %1, %2" : "=v"(r) : "v"(a), "v"(b));
    return r;   // lo16 = bf16(a), hi16 = bf16(b)
}

// ---------------- kernel 0: transpose Wqkv -> WT and Wproj -> WTp ----------------
__global__ void wt_kernel(const float* __restrict__ W, const float* __restrict__ Wp,
                          float* __restrict__ WT, float* __restrict__ WTp) {
    int idx = blockIdx.x * 256 + threadIdx.x;
    if (idx < D3_ * C_) {
        int d = idx / C_, c = idx % C_;
        WT[c * D3_ + d] = W[idx];
    } else {
        int j = idx - D3_ * C_;
        if (j < C_ * C_) {
            int d = j / C_, c = j % C_;
            WTp[c * C_ + d] = Wp[j];
        }
    }
}

// ---------------- kernel 1: qkv[b][hw][d] = sum_c x[b][c][hw] * Wqkv[d][c] ----------------
__global__ __launch_bounds__(256) void qkv_kernel(const float* __restrict__ x,
                                                  const float* __restrict__ WT,
                                                  float* __restrict__ qkv) {
    __shared__ float xs[28][128];
    __shared__ float ws[28][128];
    const int b = blockIdx.z;
    const int hw0 = blockIdx.x * 128;
    const int d0 = blockIdx.y * 128;
    const int tid = threadIdx.x;
    const int tx = tid & 15;
    const int ty = tid >> 4;
    float acc[8][8] = {};
    for (int c0 = 0; c0 < C_; c0 += 28) {
        __syncthreads();
        for (int i = tid; i < 28 * 32; i += 256) {
            int c = i >> 5, j4 = (i & 31) << 2;
            *(float4*)&xs[c][j4] = *(const float4*)(x + (((size_t)b * C_ + c0 + c) << 12) + hw0 + j4);
        }
        for (int i = tid; i < 28 * 32; i += 256) {
            int c = i >> 5, d4 = (i & 31) << 2;
            float4 v = make_float4(0.f, 0.f, 0.f, 0.f);
            if (d0 + d4 < D3_) v = *(const float4*)(WT + (size_t)(c0 + c) * D3_ + d0 + d4);
            *(float4*)&ws[c][d4] = v;
        }
        __syncthreads();
        #pragma unroll 4
        for (int c = 0; c < 28; ++c) {
            float xv[8], wv[8];
            *(float4*)&xv[0] = *(float4*)&xs[c][tx << 3];
            *(float4*)&xv[4] = *(float4*)&xs[c][(tx << 3) + 4];
            *(float4*)&wv[0] = *(float4*)&ws[c][ty << 3];
            *(float4*)&wv[4] = *(float4*)&ws[c][(ty << 3) + 4];
            #pragma unroll
            for (int i = 0; i < 8; ++i)
                #pragma unroll
                for (int j = 0; j < 8; ++j) acc[i][j] += xv[i] * wv[j];
        }
    }
    const int dbase = d0 + (ty << 3);
    if (dbase < D3_) {
        #pragma unroll
        for (int i = 0; i < 8; ++i) {
            float* dst = qkv + (size_t)((b << 12) + hw0 + (tx << 3) + i) * D3_ + dbase;
            *(float4*)dst = make_float4(acc[i][0], acc[i][1], acc[i][2], acc[i][3]);
            *(float4*)(dst + 4) = make_float4(acc[i][4], acc[i][5], acc[i][6], acc[i][7]);
        }
    }
}

// ---------------- kernel 2: windowed top-k attention, MFMA, one wave per (window, head) ----------------
__global__ __launch_bounds__(256) void attn_kernel(const float* __restrict__ qkv,
                                                   const int* __restrict__ topk,
                                                   float* __restrict__ obuf) {
    __shared__ int idxs[TOPK_];
    __shared__ __align__(16) unsigned vsT[4][32][68];   // per-wave V^T bf16 pairs: [d][k/2], pad 68
    __shared__ __align__(16) unsigned plds[4][16][68];  // per-wave P: [q][k/2], pad 68
    const int b = blockIdx.y, w = blockIdx.x;
    const int wy = w >> 4, wx = w & 15;
    const int tid = threadIdx.x;
    const int wv = tid >> 6;        // wave index = head
    const int l = tid & 63;
    const int lq = l & 15;          // q-col / k-row / d-row within fragment
    const int g = l >> 4;           // lane group
    if (tid < TOPK_) idxs[tid] = topk[w * TOPK_ + tid];
    __syncthreads();
    const int h = wv;
    const size_t bbase = (size_t)(b << 12);
    const int hwq = ((wy * 4 + (lq >> 2)) << 6) + (wx << 2) + (lq & 3);
    // ---- Q fragment (B operand): col q = lq, k-dim c = 8g + j (c>=28 zero) ----
    Frag qf;
    {
        const float* qp = qkv + (bbase + hwq) * D3_ + h * HD_ + (g << 3);
        float4 a = *(const float4*)qp;
        a.x *= SCALE_; a.y *= SCALE_; a.z *= SCALE_; a.w *= SCALE_;
        qf.u[0] = cvtpk(a.x, a.y); qf.u[1] = cvtpk(a.z, a.w);
        if (g < 3) {
            float4 c = *(const float4*)(qp + 4);
            c.x *= SCALE_; c.y *= SCALE_; c.z *= SCALE_; c.w *= SCALE_;
            qf.u[2] = cvtpk(c.x, c.y); qf.u[3] = cvtpk(c.z, c.w);
        } else { qf.u[2] = 0; qf.u[3] = 0; }
    }
    // ---- K fragments (A operand), 8 tiles: row k = 16m+lq, k-dim c = 8g+j ----
    Frag kf[8];
    #pragma unroll
    for (int m = 0; m < 8; ++m) {
        const int kr = idxs[(m << 4) + lq];
        const float* kp = qkv + (bbase + kr) * D3_ + C_ + h * HD_ + (g << 3);
        float4 a = *(const float4*)kp;
        float4 c = *(const float4*)(kp + 4);   // g==3: c=28..31 garbage, nulled by Q zeros
        kf[m].u[0] = cvtpk(a.x, a.y); kf[m].u[1] = cvtpk(a.z, a.w);
        kf[m].u[2] = cvtpk(c.x, c.y); kf[m].u[3] = cvtpk(c.z, c.w);
    }
    // ---- V stage: lane gathers rows k=2l, 2l+1; write V^T columns (conflict-free b32) ----
    {
        const float* v0 = qkv + (bbase + idxs[2 * l]) * D3_ + 2 * C_ + h * HD_;
        const float* v1 = qkv + (bbase + idxs[2 * l + 1]) * D3_ + 2 * C_ + h * HD_;
        #pragma unroll
        for (int c4 = 0; c4 < 7; ++c4) {
            float4 a = *(const float4*)(v0 + (c4 << 2));
            float4 c = *(const float4*)(v1 + (c4 << 2));
            vsT[wv][(c4 << 2) + 0][l] = cvtpk(a.x, c.x);
            vsT[wv][(c4 << 2) + 1][l] = cvtpk(a.y, c.y);
            vsT[wv][(c4 << 2) + 2][l] = cvtpk(a.z, c.z);
            vsT[wv][(c4 << 2) + 3][l] = cvtpk(a.w, c.w);
        }
    }
    // ---- QK^T: S^T[k][q], 8 MFMAs ----
    f32x4 sacc[8];
    #pragma unroll
    for (int m = 0; m < 8; ++m) {
        f32x4 z = {0.f, 0.f, 0.f, 0.f};
        sacc[m] = __builtin_amdgcn_mfma_f32_16x16x32_bf16(kf[m].s, qf.s, z, 0, 0, 0);
    }
    // ---- softmax over k (32 regs + xor16/32), all in-register ----
    float mx = -1e30f;
    #pragma unroll
    for (int m = 0; m < 8; ++m)
        #pragma unroll
        for (int r = 0; r < 4; ++r) mx = fmaxf(mx, sacc[m][r]);
    mx = fmaxf(mx, __shfl_xor(mx, 16, 64));
    mx = fmaxf(mx, __shfl_xor(mx, 32, 64));
    float sum = 0.f;
    #pragma unroll
    for (int m = 0; m < 8; ++m)
        #pragma unroll
        for (int r = 0; r < 4; ++r) { float e = __expf(sacc[m][r] - mx); sacc[m][r] = e; sum += e; }
    sum += __shfl_xor(sum, 16, 64);
    sum += __shfl_xor(sum, 32, 64);
    const float inv = 1.f / sum;
    // ---- P -> LDS bf16: k = 16m+4g+{0..3}, q = lq ----
    #pragma unroll
    for (int m = 0; m < 8; ++m) {
        unsigned u0 = cvtpk(sacc[m][0] * inv, sacc[m][1] * inv);
        unsigned u1 = cvtpk(sacc[m][2] * inv, sacc[m][3] * inv);
        *(uint2*)&plds[wv][lq][(m << 3) + (g << 1)] = make_uint2(u0, u1);
    }
    // ---- PV: O^T[d][q] = V^T @ P^T, 8 MFMAs (2 d-tiles x 4 k-steps) ----
    f32x4 oacc[2] = {};
    #pragma unroll
    for (int ks = 0; ks < 4; ++ks) {
        Frag pb;
        pb.u4 = *(const uint4*)&plds[wv][lq][(g << 2) + (ks << 4)];
        #pragma unroll
        for (int m = 0; m < 2; ++m) {
            Frag va;
            va.u4 = *(const uint4*)&vsT[wv][lq + (m << 4)][(g << 2) + (ks << 4)];
            oacc[m] = __builtin_amdgcn_mfma_f32_16x16x32_bf16(va.s, pb.s, oacc[m], 0, 0, 0);
        }
    }
    // ---- write O: lane has q=lq, d = 4g+r+16m ----
    float* orow = obuf + (bbase + hwq) * C_ + h * HD_;
    #pragma unroll
    for (int m = 0; m < 2; ++m) {
        const int d0 = (g << 2) + (m << 4);
        if (d0 < HD_)
            *(float4*)(orow + d0) = make_float4(oacc[m][0], oacc[m][1], oacc[m][2], oacc[m][3]);
    }
}

// ---------------- kernel 3: out[b][d][hw] = sum_c o[b][hw][c]*Wproj[d][c] + bproj[d] ----------------
__global__ __launch_bounds__(256) void proj_kernel(const float* __restrict__ obuf,
                                                   const float* __restrict__ WTp,
                                                   const float* __restrict__ bp,
                                                   float* __restrict__ out) {
    __shared__ float os_t[28][128];
    __shared__ float ws[28][116];
    const int b = blockIdx.y;
    const int hw0 = blockIdx.x * 128;
    const int tid = threadIdx.x;
    const int tx = tid & 15;
    const int ty = tid >> 4;
    float acc[8][8] = {};
    for (int c0 = 0; c0 < C_; c0 += 28) {
        __syncthreads();
        for (int i = tid; i < 896; i += 256) {
            int hw = i / 7, c4 = (i % 7) << 2;
            float4 v = *(const float4*)(obuf + ((size_t)((b << 12) + hw0 + hw)) * C_ + c0 + c4);
            os_t[c4][hw] = v.x; os_t[c4 + 1][hw] = v.y; os_t[c4 + 2][hw] = v.z; os_t[c4 + 3][hw] = v.w;
        }
        for (int i = tid; i < 784; i += 256) {
            int c = i / 28, d4 = (i % 28) << 2;
            *(float4*)&ws[c][d4] = *(const float4*)(WTp + (size_t)(c0 + c) * C_ + d4);
        }
        __syncthreads();
        if (ty < 14) {
            #pragma unroll 4
            for (int c = 0; c < 28; ++c) {
                float xv[8], wv[8];
                *(float4*)&xv[0] = *(float4*)&os_t[c][tx << 3];
                *(float4*)&xv[4] = *(float4*)&os_t[c][(tx << 3) + 4];
                *(float4*)&wv[0] = *(float4*)&ws[c][ty << 3];
                *(float4*)&wv[4] = *(float4*)&ws[c][(ty << 3) + 4];
                #pragma unroll
                for (int i = 0; i < 8; ++i)
                    #pragma unroll
                    for (int j = 0; j < 8; ++j) acc[i][j] += xv[i] * wv[j];
            }
        }
    }
    if (ty < 14) {
        #pragma unroll
        for (int j = 0; j < 8; ++j) {
            const int d = (ty << 3) + j;
            const float bv = bp[d];
            float* dst = out + ((size_t)(b * C_ + d) << 12) + hw0 + (tx << 3);
            *(float4*)dst = make_float4(acc[0][j] + bv, acc[1][j] + bv, acc[2][j] + bv, acc[3][j] + bv);
            *(float4*)(dst + 4) = make_float4(acc[4][j] + bv, acc[5][j] + bv, acc[6][j] + bv, acc[7][j] + bv);
        }
    }
}

extern "C" void kernel_launch(void* const* d_in, const int* in_sizes, int n_in,
                              void* d_out, int out_size, void* d_ws, size_t ws_size,
                              hipStream_t stream) {
    const float* x     = (const float*)d_in[0];
    const float* Wqkv  = (const float*)d_in[1];
    const float* Wproj = (const float*)d_in[2];
    const float* bproj = (const float*)d_in[3];
    const int*   topk  = (const int*)d_in[4];
    float* out = (float*)d_out;
    char* ws = (char*)d_ws;
    float* qkv  = (float*)ws;                                  // 88,080,384 B
    float* obuf = (float*)(ws + 88080384);                     // 29,360,128 B
    float* WT   = (float*)(ws + 88080384 + 29360128);          //    150,528 B
    float* WTp  = (float*)(ws + 88080384 + 29360128 + 150528); //     50,176 B
    wt_kernel<<<dim3((D3_ * C_ + C_ * C_ + 255) / 256), 256, 0, stream>>>(Wqkv, Wproj, WT, WTp);
    qkv_kernel<<<dim3(32, 3, 16), 256, 0, stream>>>(x, WT, qkv);
    attn_kernel<<<dim3(NWIN_, 16), 256, 0, stream>>>(qkv, topk, obuf);
    proj_kernel<<<dim3(32, 16), 256, 0, stream>>>(obuf, WTp, bproj, out);
}

// Round 7
// 165.635 us; speedup vs baseline: 2.8452x; 1.4748x over previous
//
#include <hip/hip_runtime.h>
#include <hip/hip_bf16.h>
#include <cstdint>

#define B_ 16
#define C_ 112
#define HEADS_ 4
#define HD_ 28
#define NWIN_ 256
#define TOPK_ 128
#define D3_ 336
#define SCALE_ 0.18898223650461363f

typedef __attribute__((ext_vector_type(4))) float f32x4;
typedef __attribute__((ext_vector_type(8))) short short8;
typedef unsigned uint4u __attribute__((ext_vector_type(4), aligned(4)));  // dword-aligned 16B load

union Frag { unsigned u[4]; uint4 u4; short8 s; };

__device__ inline unsigned cvtpk(float a, float b) {
    unsigned r;
    asm("v_cvt_pk_bf16_f32 %0, %1, %2" : "=v"(r) : "v"(a), "v"(b));
    return r;   // lo16 = bf16(a), hi16 = bf16(b)
}
__device__ inline float bflo(unsigned u) { return __uint_as_float(u << 16); }
__device__ inline float bfhi(unsigned u) { return __uint_as_float(u & 0xFFFF0000u); }

// ---- kernel 0: build W fragments ----
// WAq: Wqkv bf16 A-frags [ks=4][tile=21][lane=64] (uint4 each: 8 c-values packed in pairs)
// WAp_hi/lo: Wproj split-bf16 A-frags [ks=4][tile=7][lane=64]
__global__ __launch_bounds__(256) void wt_kernel(const float* __restrict__ W, const float* __restrict__ Wp,
                                                 uint4* __restrict__ WAq,
                                                 uint4* __restrict__ WAh, uint4* __restrict__ WAl) {
    const int id = blockIdx.x * 256 + threadIdx.x;
    if (id < 5376) {                       // 4*21*64
        const int ks = id / 1344, rem = id % 1344;
        const int tile = rem >> 6, l = rem & 63;
        const int d = tile * 16 + (l & 15);
        const int cb = ks * 32 + (l >> 4) * 8;
        float v[8];
        #pragma unroll
        for (int j = 0; j < 8; ++j) { int c = cb + j; v[j] = (c < C_) ? W[d * C_ + c] : 0.f; }
        uint4 o;
        o.x = cvtpk(v[0], v[1]); o.y = cvtpk(v[2], v[3]);
        o.z = cvtpk(v[4], v[5]); o.w = cvtpk(v[6], v[7]);
        WAq[id] = o;
    } else if (id < 5376 + 1792) {         // 4*7*64
        const int id2 = id - 5376;
        const int ks = id2 / 448, rem = id2 % 448;
        const int tile = rem >> 6, l = rem & 63;
        const int d = tile * 16 + (l & 15);
        const int cb = ks * 32 + (l >> 4) * 8;
        float v[8];
        #pragma unroll
        for (int j = 0; j < 8; ++j) { int c = cb + j; v[j] = (c < C_) ? Wp[d * C_ + c] : 0.f; }
        unsigned hw_[4], lw_[4];
        #pragma unroll
        for (int p = 0; p < 4; ++p) {
            unsigned hh = cvtpk(v[2 * p], v[2 * p + 1]);
            hw_[p] = hh;
            lw_[p] = cvtpk(v[2 * p] - bflo(hh), v[2 * p + 1] - bfhi(hh));
        }
        WAh[id2] = make_uint4(hw_[0], hw_[1], hw_[2], hw_[3]);
        WAl[id2] = make_uint4(lw_[0], lw_[1], lw_[2], lw_[3]);
    }
}

// ---- kernel 1: qkv_bf[b][hw][336] (bf16) = x @ Wqkv^T via MFMA ----
// block: 4 waves, tile 128hw x 112d, K=112 pad 128 in one LDS stage.
__global__ __launch_bounds__(256) void qkv_kernel(const float* __restrict__ x,
                                                  const uint4* __restrict__ WAq,
                                                  ushort* __restrict__ qkv) {
    __shared__ unsigned xs[64][132];   // bf16 pairs [c2][hw], stride 132 (16B-aligned rows, 2-way max)
    const int hw0 = blockIdx.x << 7;
    const int dblk = blockIdx.y;       // 0..2
    const int b = blockIdx.z;
    const int tid = threadIdx.x;
    for (int i = tid; i < 2048; i += 256) {
        const int c2 = i >> 5, j4 = (i & 31) << 2;
        uint4 o = make_uint4(0, 0, 0, 0);
        if (c2 < 56) {
            const float* r0 = x + (((size_t)b * C_ + 2 * c2) << 12) + hw0 + j4;
            float4 a = *(const float4*)r0;
            float4 c = *(const float4*)(r0 + 4096);
            o.x = cvtpk(a.x, c.x); o.y = cvtpk(a.y, c.y);
            o.z = cvtpk(a.z, c.z); o.w = cvtpk(a.w, c.w);
        }
        *(uint4*)&xs[c2][j4] = o;
    }
    __syncthreads();
    const int wv = tid >> 6, l = tid & 63, lq = l & 15, g = l >> 4;
    const int hwl = wv << 5;
    f32x4 acc[7][2] = {};
    #pragma unroll
    for (int ks = 0; ks < 4; ++ks) {
        Frag bf[2];
        #pragma unroll
        for (int n = 0; n < 2; ++n) {
            const int col = hwl + (n << 4) + lq;
            const int r0 = (ks << 4) + (g << 2);
            bf[n].u[0] = xs[r0][col]; bf[n].u[1] = xs[r0 + 1][col];
            bf[n].u[2] = xs[r0 + 2][col]; bf[n].u[3] = xs[r0 + 3][col];
        }
        const uint4* wp = WAq + ((ks * 21 + dblk * 7) << 6) + l;
        #pragma unroll
        for (int m = 0; m < 7; ++m) {
            Frag af; af.u4 = wp[m << 6];
            acc[m][0] = __builtin_amdgcn_mfma_f32_16x16x32_bf16(af.s, bf[0].s, acc[m][0], 0, 0, 0);
            acc[m][1] = __builtin_amdgcn_mfma_f32_16x16x32_bf16(af.s, bf[1].s, acc[m][1], 0, 0, 0);
        }
    }
    const size_t hwbase = ((size_t)b << 12) + hw0;
    #pragma unroll
    for (int m = 0; m < 7; ++m) {
        const int d0 = dblk * 112 + (m << 4) + (g << 2);
        #pragma unroll
        for (int n = 0; n < 2; ++n) {
            const int hw = hwl + (n << 4) + lq;
            uint2 o2;
            o2.x = cvtpk(acc[m][n][0], acc[m][n][1]);
            o2.y = cvtpk(acc[m][n][2], acc[m][n][3]);
            *(uint2*)(qkv + (hwbase + hw) * D3_ + d0) = o2;
        }
    }
}

// ---- kernel 2: windowed top-k attention, bf16 in, one wave per (window, head) ----
__global__ __launch_bounds__(256) void attn_kernel(const ushort* __restrict__ qkv,
                                                   const int* __restrict__ topk,
                                                   float* __restrict__ obuf) {
    __shared__ int idxs[TOPK_];
    __shared__ __align__(16) unsigned vsT[4][32][68];   // per-wave V^T bf16 pairs [d][k/2]
    __shared__ __align__(16) unsigned plds[4][16][68];  // per-wave P [q][k/2]
    const int b = blockIdx.y, w = blockIdx.x;
    const int wy = w >> 4, wx = w & 15;
    const int tid = threadIdx.x;
    const int wv = tid >> 6, l = tid & 63, lq = l & 15, g = l >> 4;
    if (tid < TOPK_) idxs[tid] = topk[w * TOPK_ + tid];
    __syncthreads();
    const int h = wv;
    const size_t bbase = (size_t)(b << 12);
    const int hwq = ((wy * 4 + (lq >> 2)) << 6) + (wx << 2) + (lq & 3);
    // Q fragment (B operand), no scale (folded into scores)
    Frag qf;
    {
        uint4u t = *(const uint4u*)(qkv + (bbase + hwq) * D3_ + h * HD_ + (g << 3));
        qf.u[0] = t[0]; qf.u[1] = t[1];
        qf.u[2] = (g == 3) ? 0u : t[2];
        qf.u[3] = (g == 3) ? 0u : t[3];
    }
    // K fragments (A operand)
    Frag kf[8];
    #pragma unroll
    for (int m = 0; m < 8; ++m) {
        const int kr = idxs[(m << 4) + lq];
        uint4u t = *(const uint4u*)(qkv + (bbase + kr) * D3_ + C_ + h * HD_ + (g << 3));
        kf[m].u[0] = t[0]; kf[m].u[1] = t[1]; kf[m].u[2] = t[2]; kf[m].u[3] = t[3];
    }
    // V gather rows 2l, 2l+1 -> transpose-pack via v_perm
    {
        const ushort* v0 = qkv + (bbase + idxs[2 * l]) * D3_ + 2 * C_ + h * HD_;
        const ushort* v1 = qkv + (bbase + idxs[2 * l + 1]) * D3_ + 2 * C_ + h * HD_;
        unsigned w0[14], w1[14];
        { uint4u a = *(const uint4u*)v0;        w0[0]=a[0]; w0[1]=a[1]; w0[2]=a[2]; w0[3]=a[3]; }
        { uint4u a = *(const uint4u*)(v0 + 8);  w0[4]=a[0]; w0[5]=a[1]; w0[6]=a[2]; w0[7]=a[3]; }
        { uint4u a = *(const uint4u*)(v0 + 16); w0[8]=a[0]; w0[9]=a[1]; w0[10]=a[2]; w0[11]=a[3]; }
        { uint2 a = *(const uint2*)(v0 + 24);   w0[12]=a.x; w0[13]=a.y; }
        { uint4u a = *(const uint4u*)v1;        w1[0]=a[0]; w1[1]=a[1]; w1[2]=a[2]; w1[3]=a[3]; }
        { uint4u a = *(const uint4u*)(v1 + 8);  w1[4]=a[0]; w1[5]=a[1]; w1[6]=a[2]; w1[7]=a[3]; }
        { uint4u a = *(const uint4u*)(v1 + 16); w1[8]=a[0]; w1[9]=a[1]; w1[10]=a[2]; w1[11]=a[3]; }
        { uint2 a = *(const uint2*)(v1 + 24);   w1[12]=a.x; w1[13]=a.y; }
        #pragma unroll
        for (int j = 0; j < 14; ++j) {
            vsT[wv][2 * j][l]     = __builtin_amdgcn_perm(w1[j], w0[j], 0x05040100);
            vsT[wv][2 * j + 1][l] = __builtin_amdgcn_perm(w1[j], w0[j], 0x07060302);
        }
    }
    // QK^T -> S^T[k][q]
    f32x4 sacc[8];
    #pragma unroll
    for (int m = 0; m < 8; ++m) {
        f32x4 z = {0.f, 0.f, 0.f, 0.f};
        sacc[m] = __builtin_amdgcn_mfma_f32_16x16x32_bf16(kf[m].s, qf.s, z, 0, 0, 0);
    }
    // scale + softmax over k (in-register, xor16/32)
    float mx = -1e30f;
    #pragma unroll
    for (int m = 0; m < 8; ++m)
        #pragma unroll
        for (int r = 0; r < 4; ++r) { sacc[m][r] *= SCALE_; mx = fmaxf(mx, sacc[m][r]); }
    mx = fmaxf(mx, __shfl_xor(mx, 16, 64));
    mx = fmaxf(mx, __shfl_xor(mx, 32, 64));
    float sum = 0.f;
    #pragma unroll
    for (int m = 0; m < 8; ++m)
        #pragma unroll
        for (int r = 0; r < 4; ++r) { float e = __expf(sacc[m][r] - mx); sacc[m][r] = e; sum += e; }
    sum += __shfl_xor(sum, 16, 64);
    sum += __shfl_xor(sum, 32, 64);
    const float inv = 1.f / sum;
    #pragma unroll
    for (int m = 0; m < 8; ++m) {
        unsigned u0 = cvtpk(sacc[m][0] * inv, sacc[m][1] * inv);
        unsigned u1 = cvtpk(sacc[m][2] * inv, sacc[m][3] * inv);
        *(uint2*)&plds[wv][lq][(m << 3) + (g << 1)] = make_uint2(u0, u1);
    }
    // PV: O^T[d][q]
    f32x4 oacc[2] = {};
    #pragma unroll
    for (int ks = 0; ks < 4; ++ks) {
        Frag pb;
        pb.u4 = *(const uint4*)&plds[wv][lq][(g << 2) + (ks << 4)];
        #pragma unroll
        for (int m = 0; m < 2; ++m) {
            Frag va;
            va.u4 = *(const uint4*)&vsT[wv][lq + (m << 4)][(g << 2) + (ks << 4)];
            oacc[m] = __builtin_amdgcn_mfma_f32_16x16x32_bf16(va.s, pb.s, oacc[m], 0, 0, 0);
        }
    }
    // write O transposed: obuf[b][c=112][hw]
    #pragma unroll
    for (int m = 0; m < 2; ++m) {
        const int d0 = (g << 2) + (m << 4);
        if (d0 < HD_) {
            #pragma unroll
            for (int r = 0; r < 4; ++r)
                obuf[(((size_t)(b * C_ + h * HD_ + d0 + r)) << 12) + hwq] = oacc[m][r];
        }
    }
}

// ---- kernel 3: out = o @ Wproj^T + b via split-bf16 MFMA (fp32-class accuracy) ----
__global__ __launch_bounds__(256) void proj_kernel(const float* __restrict__ obuf,
                                                   const uint4* __restrict__ WAh,
                                                   const uint4* __restrict__ WAl,
                                                   const float* __restrict__ bp,
                                                   float* __restrict__ out) {
    __shared__ unsigned xh[64][132];
    __shared__ unsigned xl[64][132];
    const int hw0 = blockIdx.x << 7;
    const int b = blockIdx.y;
    const int tid = threadIdx.x;
    for (int i = tid; i < 2048; i += 256) {
        const int c2 = i >> 5, j4 = (i & 31) << 2;
        uint4 oh = make_uint4(0, 0, 0, 0), ol = make_uint4(0, 0, 0, 0);
        if (c2 < 56) {
            const float* r0 = obuf + (((size_t)b * C_ + 2 * c2) << 12) + hw0 + j4;
            float4 a = *(const float4*)r0;
            float4 c = *(const float4*)(r0 + 4096);
            unsigned t;
            t = cvtpk(a.x, c.x); oh.x = t; ol.x = cvtpk(a.x - bflo(t), c.x - bfhi(t));
            t = cvtpk(a.y, c.y); oh.y = t; ol.y = cvtpk(a.y - bflo(t), c.y - bfhi(t));
            t = cvtpk(a.z, c.z); oh.z = t; ol.z = cvtpk(a.z - bflo(t), c.z - bfhi(t));
            t = cvtpk(a.w, c.w); oh.w = t; ol.w = cvtpk(a.w - bflo(t), c.w - bfhi(t));
        }
        *(uint4*)&xh[c2][j4] = oh;
        *(uint4*)&xl[c2][j4] = ol;
    }
    __syncthreads();
    const int wv = tid >> 6, l = tid & 63, lq = l & 15, g = l >> 4;
    const int hwl = wv << 5;
    f32x4 acc[7][2] = {};
    #pragma unroll
    for (int ks = 0; ks < 4; ++ks) {
        Frag bh[2], bl[2];
        #pragma unroll
        for (int n = 0; n < 2; ++n) {
            const int col = hwl + (n << 4) + lq;
            const int r0 = (ks << 4) + (g << 2);
            bh[n].u[0] = xh[r0][col]; bh[n].u[1] = xh[r0 + 1][col];
            bh[n].u[2] = xh[r0 + 2][col]; bh[n].u[3] = xh[r0 + 3][col];
            bl[n].u[0] = xl[r0][col]; bl[n].u[1] = xl[r0 + 1][col];
            bl[n].u[2] = xl[r0 + 2][col]; bl[n].u[3] = xl[r0 + 3][col];
        }
        const uint4* wph = WAh + ((ks * 7) << 6) + l;
        const uint4* wpl = WAl + ((ks * 7) << 6) + l;
        #pragma unroll
        for (int m = 0; m < 7; ++m) {
            Frag ah, al;
            ah.u4 = wph[m << 6];
            al.u4 = wpl[m << 6];
            #pragma unroll
            for (int n = 0; n < 2; ++n) {
                acc[m][n] = __builtin_amdgcn_mfma_f32_16x16x32_bf16(ah.s, bh[n].s, acc[m][n], 0, 0, 0);
                acc[m][n] = __builtin_amdgcn_mfma_f32_16x16x32_bf16(ah.s, bl[n].s, acc[m][n], 0, 0, 0);
                acc[m][n] = __builtin_amdgcn_mfma_f32_16x16x32_bf16(al.s, bh[n].s, acc[m][n], 0, 0, 0);
            }
        }
    }
    #pragma unroll
    for (int m = 0; m < 7; ++m) {
        const int d0 = (m << 4) + (g << 2);
        const float4 bias = *(const float4*)(bp + d0);
        #pragma unroll
        for (int n = 0; n < 2; ++n) {
            const int hw = hw0 + hwl + (n << 4) + lq;
            out[(((size_t)(b * C_ + d0 + 0)) << 12) + hw] = acc[m][n][0] + bias.x;
            out[(((size_t)(b * C_ + d0 + 1)) << 12) + hw] = acc[m][n][1] + bias.y;
            out[(((size_t)(b * C_ + d0 + 2)) << 12) + hw] = acc[m][n][2] + bias.z;
            out[(((size_t)(b * C_ + d0 + 3)) << 12) + hw] = acc[m][n][3] + bias.w;
        }
    }
}

extern "C" void kernel_launch(void* const* d_in, const int* in_sizes, int n_in,
                              void* d_out, int out_size, void* d_ws, size_t ws_size,
                              hipStream_t stream) {
    const float* x     = (const float*)d_in[0];
    const float* Wqkv  = (const float*)d_in[1];
    const float* Wproj = (const float*)d_in[2];
    const float* bproj = (const float*)d_in[3];
    const int*   topk  = (const int*)d_in[4];
    float* out = (float*)d_out;
    char* ws = (char*)d_ws;
    ushort* qkv  = (ushort*)ws;                        // 44,040,192 B (bf16 [16][4096][336])
    float*  obuf = (float*)(ws + 44040192);            // 29,360,128 B (fp32 [16][112][4096])
    uint4*  WAq  = (uint4*)(ws + 44040192 + 29360128); //     86,016 B
    uint4*  WAh  = (uint4*)(ws + 44040192 + 29360128 + 86016);          // 28,672 B
    uint4*  WAl  = (uint4*)(ws + 44040192 + 29360128 + 86016 + 28672);  // 28,672 B
    wt_kernel<<<28, 256, 0, stream>>>(Wqkv, Wproj, WAq, WAh, WAl);
    qkv_kernel<<<dim3(32, 3, 16), 256, 0, stream>>>(x, WAq, qkv);
    attn_kernel<<<dim3(NWIN_, 16), 256, 0, stream>>>(qkv, topk, obuf);
    proj_kernel<<<dim3(32, 16), 256, 0, stream>>>(obuf, WAh, WAl, bproj, out);
}

// Round 8
// 155.554 us; speedup vs baseline: 3.0296x; 1.0648x over previous
//
#include <hip/hip_runtime.h>
#include <hip/hip_bf16.h>
#include <cstdint>

#define B_ 16
#define C_ 112
#define HEADS_ 4
#define HD_ 28
#define NWIN_ 256
#define TOPK_ 128
#define D3_ 336
#define SCALE_ 0.18898223650461363f

typedef __attribute__((ext_vector_type(4))) float f32x4;
typedef __attribute__((ext_vector_type(8))) short short8;
typedef unsigned uint4u __attribute__((ext_vector_type(4), aligned(4)));  // dword-aligned 16B load

union Frag { unsigned u[4]; uint4 u4; short8 s; };

__device__ inline unsigned cvtpk(float a, float b) {
    unsigned r;
    asm("v_cvt_pk_bf16_f32 %0, %1, %2" : "=v"(r) : "v"(a), "v"(b));
    return r;   // lo16 = bf16(a), hi16 = bf16(b)
}
__device__ inline float bflo(unsigned u) { return __uint_as_float(u << 16); }
__device__ inline float bfhi(unsigned u) { return __uint_as_float(u & 0xFFFF0000u); }

// ---- kernel 0: build W fragments ----
// WAq: Wqkv bf16 A-frags [ks=4][tile=21][lane=64]; WAh/WAl: Wproj split-bf16 A-frags [ks=4][tile=7][lane=64]
__global__ __launch_bounds__(256) void wt_kernel(const float* __restrict__ W, const float* __restrict__ Wp,
                                                 uint4* __restrict__ WAq,
                                                 uint4* __restrict__ WAh, uint4* __restrict__ WAl) {
    const int id = blockIdx.x * 256 + threadIdx.x;
    if (id < 5376) {                       // 4*21*64
        const int ks = id / 1344, rem = id % 1344;
        const int tile = rem >> 6, l = rem & 63;
        const int d = tile * 16 + (l & 15);
        const int cb = ks * 32 + (l >> 4) * 8;
        float v[8];
        #pragma unroll
        for (int j = 0; j < 8; ++j) { int c = cb + j; v[j] = (c < C_) ? W[d * C_ + c] : 0.f; }
        uint4 o;
        o.x = cvtpk(v[0], v[1]); o.y = cvtpk(v[2], v[3]);
        o.z = cvtpk(v[4], v[5]); o.w = cvtpk(v[6], v[7]);
        WAq[id] = o;
    } else if (id < 5376 + 1792) {         // 4*7*64
        const int id2 = id - 5376;
        const int ks = id2 / 448, rem = id2 % 448;
        const int tile = rem >> 6, l = rem & 63;
        const int d = tile * 16 + (l & 15);
        const int cb = ks * 32 + (l >> 4) * 8;
        float v[8];
        #pragma unroll
        for (int j = 0; j < 8; ++j) { int c = cb + j; v[j] = (c < C_) ? Wp[d * C_ + c] : 0.f; }
        unsigned hw_[4], lw_[4];
        #pragma unroll
        for (int p = 0; p < 4; ++p) {
            unsigned hh = cvtpk(v[2 * p], v[2 * p + 1]);
            hw_[p] = hh;
            lw_[p] = cvtpk(v[2 * p] - bflo(hh), v[2 * p + 1] - bfhi(hh));
        }
        WAh[id2] = make_uint4(hw_[0], hw_[1], hw_[2], hw_[3]);
        WAl[id2] = make_uint4(lw_[0], lw_[1], lw_[2], lw_[3]);
    }
}

// ---- kernel 1: qkv_bf[b][hw][336] (bf16) = x @ Wqkv^T via MFMA ----
__global__ __launch_bounds__(256) void qkv_kernel(const float* __restrict__ x,
                                                  const uint4* __restrict__ WAq,
                                                  ushort* __restrict__ qkv) {
    __shared__ unsigned xs[64][132];   // bf16 pairs [c2][hw]
    const int hw0 = blockIdx.x << 7;
    const int dblk = blockIdx.y;       // 0..2
    const int b = blockIdx.z;
    const int tid = threadIdx.x;
    for (int i = tid; i < 2048; i += 256) {
        const int c2 = i >> 5, j4 = (i & 31) << 2;
        uint4 o = make_uint4(0, 0, 0, 0);
        if (c2 < 56) {
            const float* r0 = x + (((size_t)b * C_ + 2 * c2) << 12) + hw0 + j4;
            float4 a = *(const float4*)r0;
            float4 c = *(const float4*)(r0 + 4096);
            o.x = cvtpk(a.x, c.x); o.y = cvtpk(a.y, c.y);
            o.z = cvtpk(a.z, c.z); o.w = cvtpk(a.w, c.w);
        }
        *(uint4*)&xs[c2][j4] = o;
    }
    __syncthreads();
    const int wv = tid >> 6, l = tid & 63, lq = l & 15, g = l >> 4;
    const int hwl = wv << 5;
    f32x4 acc[7][2] = {};
    #pragma unroll
    for (int ks = 0; ks < 4; ++ks) {
        Frag bf[2];
        #pragma unroll
        for (int n = 0; n < 2; ++n) {
            const int col = hwl + (n << 4) + lq;
            const int r0 = (ks << 4) + (g << 2);
            bf[n].u[0] = xs[r0][col]; bf[n].u[1] = xs[r0 + 1][col];
            bf[n].u[2] = xs[r0 + 2][col]; bf[n].u[3] = xs[r0 + 3][col];
        }
        const uint4* wp = WAq + ((ks * 21 + dblk * 7) << 6) + l;
        #pragma unroll
        for (int m = 0; m < 7; ++m) {
            Frag af; af.u4 = wp[m << 6];
            acc[m][0] = __builtin_amdgcn_mfma_f32_16x16x32_bf16(af.s, bf[0].s, acc[m][0], 0, 0, 0);
            acc[m][1] = __builtin_amdgcn_mfma_f32_16x16x32_bf16(af.s, bf[1].s, acc[m][1], 0, 0, 0);
        }
    }
    const size_t hwbase = ((size_t)b << 12) + hw0;
    #pragma unroll
    for (int m = 0; m < 7; ++m) {
        const int d0 = dblk * 112 + (m << 4) + (g << 2);
        #pragma unroll
        for (int n = 0; n < 2; ++n) {
            const int hw = hwl + (n << 4) + lq;
            uint2 o2;
            o2.x = cvtpk(acc[m][n][0], acc[m][n][1]);
            o2.y = cvtpk(acc[m][n][2], acc[m][n][3]);
            *(uint2*)(qkv + (hwbase + hw) * D3_ + d0) = o2;
        }
    }
}

// ---- kernel 2: fused windowed top-k attention + output projection ----
// one block per (b, window); wave = head for attn part; proj split-bf16 fused at the end.
__global__ __launch_bounds__(256) void attn_kernel(const ushort* __restrict__ qkv,
                                                   const int* __restrict__ topk,
                                                   const uint4* __restrict__ WAh,
                                                   const uint4* __restrict__ WAl,
                                                   const float* __restrict__ bp,
                                                   float* __restrict__ out) {
    __shared__ int idxs[TOPK_];
    __shared__ __align__(16) unsigned vsT[4][32][68];   // per-wave V^T bf16 pairs [d][k/2]
    __shared__ __align__(16) unsigned plds[4][16][68];  // per-wave P [q][k/2]; later aliased as os[128][17] fp32
    const int b = blockIdx.y, w = blockIdx.x;
    const int wy = w >> 4, wx = w & 15;
    const int tid = threadIdx.x;
    const int wv = tid >> 6, l = tid & 63, lq = l & 15, g = l >> 4;
    if (tid < TOPK_) idxs[tid] = topk[w * TOPK_ + tid];
    __syncthreads();
    const int h = wv;
    const size_t bbase = (size_t)(b << 12);
    const int hwq = ((wy * 4 + (lq >> 2)) << 6) + (wx << 2) + (lq & 3);
    // Q fragment (B operand), scale folded into scores
    Frag qf;
    {
        uint4u t = *(const uint4u*)(qkv + (bbase + hwq) * D3_ + h * HD_ + (g << 3));
        qf.u[0] = t[0]; qf.u[1] = t[1];
        qf.u[2] = (g == 3) ? 0u : t[2];
        qf.u[3] = (g == 3) ? 0u : t[3];
    }
    // K fragments (A operand)
    Frag kf[8];
    #pragma unroll
    for (int m = 0; m < 8; ++m) {
        const int kr = idxs[(m << 4) + lq];
        uint4u t = *(const uint4u*)(qkv + (bbase + kr) * D3_ + C_ + h * HD_ + (g << 3));
        kf[m].u[0] = t[0]; kf[m].u[1] = t[1]; kf[m].u[2] = t[2]; kf[m].u[3] = t[3];
    }
    // V gather rows 2l, 2l+1 -> transpose-pack via v_perm
    {
        const ushort* v0 = qkv + (bbase + idxs[2 * l]) * D3_ + 2 * C_ + h * HD_;
        const ushort* v1 = qkv + (bbase + idxs[2 * l + 1]) * D3_ + 2 * C_ + h * HD_;
        unsigned w0[14], w1[14];
        { uint4u a = *(const uint4u*)v0;        w0[0]=a[0]; w0[1]=a[1]; w0[2]=a[2]; w0[3]=a[3]; }
        { uint4u a = *(const uint4u*)(v0 + 8);  w0[4]=a[0]; w0[5]=a[1]; w0[6]=a[2]; w0[7]=a[3]; }
        { uint4u a = *(const uint4u*)(v0 + 16); w0[8]=a[0]; w0[9]=a[1]; w0[10]=a[2]; w0[11]=a[3]; }
        { uint2 a = *(const uint2*)(v0 + 24);   w0[12]=a.x; w0[13]=a.y; }
        { uint4u a = *(const uint4u*)v1;        w1[0]=a[0]; w1[1]=a[1]; w1[2]=a[2]; w1[3]=a[3]; }
        { uint4u a = *(const uint4u*)(v1 + 8);  w1[4]=a[0]; w1[5]=a[1]; w1[6]=a[2]; w1[7]=a[3]; }
        { uint4u a = *(const uint4u*)(v1 + 16); w1[8]=a[0]; w1[9]=a[1]; w1[10]=a[2]; w1[11]=a[3]; }
        { uint2 a = *(const uint2*)(v1 + 24);   w1[12]=a.x; w1[13]=a.y; }
        #pragma unroll
        for (int j = 0; j < 14; ++j) {
            vsT[wv][2 * j][l]     = __builtin_amdgcn_perm(w1[j], w0[j], 0x05040100);
            vsT[wv][2 * j + 1][l] = __builtin_amdgcn_perm(w1[j], w0[j], 0x07060302);
        }
    }
    // QK^T -> S^T[k][q]
    f32x4 sacc[8];
    #pragma unroll
    for (int m = 0; m < 8; ++m) {
        f32x4 z = {0.f, 0.f, 0.f, 0.f};
        sacc[m] = __builtin_amdgcn_mfma_f32_16x16x32_bf16(kf[m].s, qf.s, z, 0, 0, 0);
    }
    // scale + softmax over k (in-register, xor16/32)
    float mx = -1e30f;
    #pragma unroll
    for (int m = 0; m < 8; ++m)
        #pragma unroll
        for (int r = 0; r < 4; ++r) { sacc[m][r] *= SCALE_; mx = fmaxf(mx, sacc[m][r]); }
    mx = fmaxf(mx, __shfl_xor(mx, 16, 64));
    mx = fmaxf(mx, __shfl_xor(mx, 32, 64));
    float sum = 0.f;
    #pragma unroll
    for (int m = 0; m < 8; ++m)
        #pragma unroll
        for (int r = 0; r < 4; ++r) { float e = __expf(sacc[m][r] - mx); sacc[m][r] = e; sum += e; }
    sum += __shfl_xor(sum, 16, 64);
    sum += __shfl_xor(sum, 32, 64);
    const float inv = 1.f / sum;
    #pragma unroll
    for (int m = 0; m < 8; ++m) {
        unsigned u0 = cvtpk(sacc[m][0] * inv, sacc[m][1] * inv);
        unsigned u1 = cvtpk(sacc[m][2] * inv, sacc[m][3] * inv);
        *(uint2*)&plds[wv][lq][(m << 3) + (g << 1)] = make_uint2(u0, u1);
    }
    // PV: O^T[d][q]
    f32x4 oacc[2] = {};
    #pragma unroll
    for (int ks = 0; ks < 4; ++ks) {
        Frag pb;
        pb.u4 = *(const uint4*)&plds[wv][lq][(g << 2) + (ks << 4)];
        #pragma unroll
        for (int m = 0; m < 2; ++m) {
            Frag va;
            va.u4 = *(const uint4*)&vsT[wv][lq + (m << 4)][(g << 2) + (ks << 4)];
            oacc[m] = __builtin_amdgcn_mfma_f32_16x16x32_bf16(va.s, pb.s, oacc[m], 0, 0, 0);
        }
    }
    // ================= fused projection =================
    __syncthreads();   // all waves done reading plds/vsT
    float* os = (float*)&plds[0][0][0];   // os[c][q], stride 17; c = h*28+d
    // zero pad rows c = 112..127 (avoid NaN garbage; A-frags there are zero but 0*NaN = NaN)
    for (int i = 1904 + tid; i < 2176; i += 256) os[i] = 0.f;
    #pragma unroll
    for (int m = 0; m < 2; ++m) {
        const int d0 = (g << 2) + (m << 4);
        if (d0 < HD_) {
            #pragma unroll
            for (int r = 0; r < 4; ++r)
                os[(h * HD_ + d0 + r) * 17 + lq] = oacc[m][r];
        }
    }
    __syncthreads();
    // out[d][hw] = Wp[d][:] . O[hw][:] + bias ; wave wv handles d-tiles m = 2wv, 2wv+1
    f32x4 pacc[2] = {};
    #pragma unroll
    for (int ks = 0; ks < 4; ++ks) {
        const int cb = (g << 3) + (ks << 5);
        float v[8];
        #pragma unroll
        for (int j = 0; j < 8; ++j) v[j] = os[(cb + j) * 17 + lq];
        Frag bh, bl;
        #pragma unroll
        for (int p = 0; p < 4; ++p) {
            unsigned hh = cvtpk(v[2 * p], v[2 * p + 1]);
            bh.u[p] = hh;
            bl.u[p] = cvtpk(v[2 * p] - bflo(hh), v[2 * p + 1] - bfhi(hh));
        }
        #pragma unroll
        for (int mi = 0; mi < 2; ++mi) {
            const int m = (wv << 1) + mi;
            if (m < 7) {
                Frag ah, al;
                ah.u4 = WAh[((ks * 7 + m) << 6) + l];
                al.u4 = WAl[((ks * 7 + m) << 6) + l];
                pacc[mi] = __builtin_amdgcn_mfma_f32_16x16x32_bf16(ah.s, bh.s, pacc[mi], 0, 0, 0);
                pacc[mi] = __builtin_amdgcn_mfma_f32_16x16x32_bf16(ah.s, bl.s, pacc[mi], 0, 0, 0);
                pacc[mi] = __builtin_amdgcn_mfma_f32_16x16x32_bf16(al.s, bh.s, pacc[mi], 0, 0, 0);
            }
        }
    }
    #pragma unroll
    for (int mi = 0; mi < 2; ++mi) {
        const int m = (wv << 1) + mi;
        if (m < 7) {
            const int d0 = (m << 4) + (g << 2);
            const float4 bias = *(const float4*)(bp + d0);
            out[(((size_t)(b * C_ + d0 + 0)) << 12) + hwq] = pacc[mi][0] + bias.x;
            out[(((size_t)(b * C_ + d0 + 1)) << 12) + hwq] = pacc[mi][1] + bias.y;
            out[(((size_t)(b * C_ + d0 + 2)) << 12) + hwq] = pacc[mi][2] + bias.z;
            out[(((size_t)(b * C_ + d0 + 3)) << 12) + hwq] = pacc[mi][3] + bias.w;
        }
    }
}

extern "C" void kernel_launch(void* const* d_in, const int* in_sizes, int n_in,
                              void* d_out, int out_size, void* d_ws, size_t ws_size,
                              hipStream_t stream) {
    const float* x     = (const float*)d_in[0];
    const float* Wqkv  = (const float*)d_in[1];
    const float* Wproj = (const float*)d_in[2];
    const float* bproj = (const float*)d_in[3];
    const int*   topk  = (const int*)d_in[4];
    float* out = (float*)d_out;
    char* ws = (char*)d_ws;
    ushort* qkv = (ushort*)ws;                         // 44,040,192 B (bf16 [16][4096][336])
    uint4*  WAq = (uint4*)(ws + 44040192);             //     86,016 B
    uint4*  WAh = (uint4*)(ws + 44040192 + 86016);     //     28,672 B
    uint4*  WAl = (uint4*)(ws + 44040192 + 86016 + 28672);
    wt_kernel<<<28, 256, 0, stream>>>(Wqkv, Wproj, WAq, WAh, WAl);
    qkv_kernel<<<dim3(32, 3, 16), 256, 0, stream>>>(x, WAq, qkv);
    attn_kernel<<<dim3(NWIN_, 16), 256, 0, stream>>>(qkv, topk, WAh, WAl, bproj, out);
}